// Round 6
// baseline (1082.260 us; speedup 1.0000x reference)
//
#include <hip/hip_runtime.h>
#include <math.h>

#define NBATCH 8
#define NPTS 4096
#define NPOINT 1024
#define NSAMPLE 32
#define PTDIM 67        // 3 xyz + 64 feat
#define BIGF 1e10f

// DPP ctrl encodings (gfx9/CDNA)
#define DPP_QUAD_XOR1 0xB1   // quad_perm [1,0,3,2]
#define DPP_QUAD_XOR2 0x4E   // quad_perm [2,3,0,1]
#define DPP_ROW_HALF_MIRROR 0x141
#define DPP_ROW_MIRROR 0x140
#define DPP_ROW_BCAST15 0x142
#define DPP_ROW_BCAST31 0x143

// self-as-old DPP moves: un-sourced lanes keep self -> combine is a no-op there
template <int CTRL>
__device__ inline float dpp_mov_f(float v) {
  int i = __float_as_int(v);
  return __int_as_float(__builtin_amdgcn_update_dpp(i, i, CTRL, 0xf, 0xf, false));
}
template <int CTRL>
__device__ inline unsigned dpp_mov_u(unsigned v) {
  return (unsigned)__builtin_amdgcn_update_dpp((int)v, (int)v, CTRL, 0xf, 0xf, false);
}
// lexicographic u64 (hi,lo) min combine over a DPP pattern (VALU-only)
template <int CTRL>
__device__ inline void dpp_min2(unsigned& hi, unsigned& lo) {
  unsigned nh = dpp_mov_u<CTRL>(hi);
  unsigned nl = dpp_mov_u<CTRL>(lo);
  bool take = (nh < hi) || (nh == hi && nl < lo);
  hi = take ? nh : hi;
  lo = take ? nl : lo;
}
// monotone map f32 -> u32 (ascending order preserved, incl. negatives)
__device__ inline unsigned fmap(float d) {
  unsigned b = __float_as_uint(d);
  return ((int)b < 0) ? ~b : (b | 0x80000000u);
}
#define FMAP_INF 0xFF800000u   // fmap(+INF)

// ---------------------------------------------------------------------------
// F1: fused FPS (blocks 0..7; also emits SoA xyz) + MLP (blocks 8..135).
// LDS overlaid via char buffer.
// ---------------------------------------------------------------------------
struct FpsS {
  unsigned long long slots[2][4];
  int cidxS[NPOINT];
  float4 C[NPTS];                                  // packed coords: 1 b128/lookup
};
struct MlpS {
  float w0[64 * 64], w1[64 * 64], w2[128 * 64];
  float bb0[64], ss0[64], ee0[64];
  float bb1[64], ss1[64], ee1[64];
  float bb2[128], ss2[128], ee2[128];
};
#define F1_SMEM (sizeof(MlpS) > sizeof(FpsS) ? sizeof(MlpS) : sizeof(FpsS))

// FPS: one block per batch, 256 thr, 16 pts/lane in VGPRs. Split-phase wave
// reduce: v_max_f32-DPP ladder -> readlane63 -> v_min_u32-DPP ladder ->
// readlane63. Cross-wave combine via TAGGED SLOTS + volatile LDS spin (NO
// s_barrier in the 1024-step loop): slot = (distbits<<32)|(tag<<12)|(4095-j),
// tag = t+1 (tags equal across compared slots -> ordering unchanged). Parity
// double-buffer + monotone tags make the race safe: a wave cannot start step
// t+2's write before every wave finished step t's read (its t+1 poll waits on
// all t+1 writes, which follow each wave's t read).
// Exact f32 replication of jnp: ((dx*dx+dy*dy)+dz*dz), min, argmax first-idx.
// (bit-equality qualify is exact: sums of squares never produce -0)
__device__ void fps_body(char* smemRaw, const float* __restrict__ pts,
                         int* __restrict__ cidx, float* __restrict__ X,
                         float* __restrict__ Y, float* __restrict__ Z) {
  FpsS* S = (FpsS*)smemRaw;
  volatile unsigned long long* vs = (volatile unsigned long long*)&S->slots[0][0];
  const int b = blockIdx.x, tid = threadIdx.x;
  const int w = tid >> 6, lane = tid & 63;
  const float* pb = pts + (size_t)b * NPTS * PTDIM;
  float px[16], py[16], pz[16], dl[16];
  #pragma unroll
  for (int k = 0; k < 16; k++) {
    int j = tid + (k << 8);
    const float* pj = pb + (size_t)j * PTDIM;
    float x = pj[0], y = pj[1], z = pj[2];
    px[k] = x; py[k] = y; pz[k] = z;
    S->C[j] = make_float4(x, y, z, 0.0f);
    X[b * NPTS + j] = x; Y[b * NPTS + j] = y; Z[b * NPTS + j] = z;  // SoA out
    dl[k] = BIGF;
  }
  if (tid < 8) ((unsigned long long*)&S->slots[0][0])[tid] = 0;  // tag 0 != any t+1
  __syncthreads();
  int f = 0;
  float4 c0 = S->C[0];
  float cx = c0.x, cy = c0.y, cz = c0.z;
  for (int t = 0; t < NPOINT; t++) {
    if (tid == 0) S->cidxS[t] = f;                 // emit BEFORE update
    float bv = -1.0f; int bi = 0;
    #pragma unroll
    for (int k = 0; k < 16; k++) {
      float dx = __fsub_rn(px[k], cx);
      float dy = __fsub_rn(py[k], cy);
      float dz = __fsub_rn(pz[k], cz);
      float d = __fadd_rn(__fadd_rn(__fmul_rn(dx, dx), __fmul_rn(dy, dy)), __fmul_rn(dz, dz));
      float nd = fminf(dl[k], d);
      dl[k] = nd;
      if (nd > bv) { bv = nd; bi = tid + (k << 8); }  // ascending j -> first-max
    }
    // phase 1: wave max of bv (2 instr/level)
    float m = bv;
    m = fmaxf(m, dpp_mov_f<DPP_QUAD_XOR1>(m));
    m = fmaxf(m, dpp_mov_f<DPP_QUAD_XOR2>(m));
    m = fmaxf(m, dpp_mov_f<DPP_ROW_HALF_MIRROR>(m));
    m = fmaxf(m, dpp_mov_f<DPP_ROW_MIRROR>(m));
    m = fmaxf(m, dpp_mov_f<DPP_ROW_BCAST15>(m));
    m = fmaxf(m, dpp_mov_f<DPP_ROW_BCAST31>(m));   // lane63 = wave max
    unsigned wmaxbits = (unsigned)__builtin_amdgcn_readlane(__float_as_int(m), 63);
    // phase 2: min index among lanes holding the max
    unsigned cand = (__float_as_uint(bv) == wmaxbits) ? (unsigned)bi : 0xFFFFFFFFu;
    cand = min(cand, dpp_mov_u<DPP_QUAD_XOR1>(cand));
    cand = min(cand, dpp_mov_u<DPP_QUAD_XOR2>(cand));
    cand = min(cand, dpp_mov_u<DPP_ROW_HALF_MIRROR>(cand));
    cand = min(cand, dpp_mov_u<DPP_ROW_MIRROR>(cand));
    cand = min(cand, dpp_mov_u<DPP_ROW_BCAST15>(cand));
    cand = min(cand, dpp_mov_u<DPP_ROW_BCAST31>(cand));  // lane63 = min j
    unsigned jmin = (unsigned)__builtin_amdgcn_readlane((int)cand, 63);
    const unsigned tag = (unsigned)t + 1u;         // 1..1024, fits bits [12..22]
    const int base = (t & 1) * 4;
    if (lane == 0)
      vs[base + w] = ((unsigned long long)wmaxbits << 32) |
                     ((unsigned long long)tag << 12) |
                     (unsigned long long)(NPTS - 1 - jmin);  // bigger = smaller idx
    // data-barrier: spin until all 4 slots carry this step's tag
    unsigned long long s0, s1, s2, s3;
    do {
      s0 = vs[base + 0]; s1 = vs[base + 1]; s2 = vs[base + 2]; s3 = vs[base + 3];
    } while ((((unsigned)s0) >> 12) != tag || (((unsigned)s1) >> 12) != tag ||
             (((unsigned)s2) >> 12) != tag || (((unsigned)s3) >> 12) != tag);
    unsigned long long m0 = s0 > s1 ? s0 : s1;
    unsigned long long m1 = s2 > s3 ? s2 : s3;
    unsigned long long best = m0 > m1 ? m0 : m1;
    f = NPTS - 1 - (int)(best & 0xFFFull);
    float4 cc = S->C[f];                           // ONE b128 same-addr broadcast
    cx = cc.x; cy = cc.y; cz = cc.z;
  }
  __syncthreads();
  for (int i = tid; i < NPOINT; i += 256) cidx[b * NPOINT + i] = S->cidxS[i];
}

// MLP over ALL points (MLP∘gather == gather∘MLP). Thread-per-row, weights in
// LDS (broadcast reads), fully unrolled so x/h stay in VGPRs.
__device__ void mlp_body(char* smemRaw, const float* __restrict__ pts,
    const float* __restrict__ W0, const float* __restrict__ B0, const float* __restrict__ G0, const float* __restrict__ E0,
    const float* __restrict__ W1, const float* __restrict__ B1, const float* __restrict__ G1, const float* __restrict__ E1,
    const float* __restrict__ W2, const float* __restrict__ B2, const float* __restrict__ G2, const float* __restrict__ E2,
    float* __restrict__ mfeat) {
  MlpS* S = (MlpS*)smemRaw;
  const float INVS = 0.99999500003750f;            // 1/sqrt(1+1e-5)
  const int t = threadIdx.x;
  for (int i = t; i < 4096; i += 256) { S->w0[i] = W0[i]; S->w1[i] = W1[i]; }
  for (int i = t; i < 8192; i += 256) { S->w2[i] = W2[i]; }
  if (t < 64) {
    S->bb0[t] = B0[t]; S->ss0[t] = G0[t] * INVS; S->ee0[t] = E0[t];
    S->bb1[t] = B1[t]; S->ss1[t] = G1[t] * INVS; S->ee1[t] = E1[t];
  }
  if (t < 128) { S->bb2[t] = B2[t]; S->ss2[t] = G2[t] * INVS; S->ee2[t] = E2[t]; }
  __syncthreads();

  const size_t r = (size_t)(blockIdx.x - 8) * 256 + t;   // row 0..32767
  const float* xr = pts + r * PTDIM + 3;
  float x[64];
  #pragma unroll
  for (int c = 0; c < 64; c++) x[c] = xr[c];

  float h1[64];
  #pragma unroll
  for (int o = 0; o < 64; o++) {
    float acc = S->bb0[o];
    #pragma unroll
    for (int c = 0; c < 64; c += 4) {
      float4 wv = *(const float4*)&S->w0[o * 64 + c];
      acc = fmaf(wv.x, x[c], acc);
      acc = fmaf(wv.y, x[c + 1], acc);
      acc = fmaf(wv.z, x[c + 2], acc);
      acc = fmaf(wv.w, x[c + 3], acc);
    }
    h1[o] = fmaxf(fmaf(acc, S->ss0[o], S->ee0[o]), 0.0f);
  }
  float h2[64];
  #pragma unroll
  for (int o = 0; o < 64; o++) {
    float acc = S->bb1[o];
    #pragma unroll
    for (int c = 0; c < 64; c += 4) {
      float4 wv = *(const float4*)&S->w1[o * 64 + c];
      acc = fmaf(wv.x, h1[c], acc);
      acc = fmaf(wv.y, h1[c + 1], acc);
      acc = fmaf(wv.z, h1[c + 2], acc);
      acc = fmaf(wv.w, h1[c + 3], acc);
    }
    h2[o] = fmaxf(fmaf(acc, S->ss1[o], S->ee1[o]), 0.0f);
  }
  float* orow = mfeat + r * 128;
  #pragma unroll
  for (int o = 0; o < 128; o += 4) {
    float a0 = S->bb2[o], a1 = S->bb2[o + 1], a2 = S->bb2[o + 2], a3 = S->bb2[o + 3];
    #pragma unroll
    for (int c = 0; c < 64; c += 4) {
      float4 wv0 = *(const float4*)&S->w2[(o    ) * 64 + c];
      float4 wv1 = *(const float4*)&S->w2[(o + 1) * 64 + c];
      float4 wv2 = *(const float4*)&S->w2[(o + 2) * 64 + c];
      float4 wv3 = *(const float4*)&S->w2[(o + 3) * 64 + c];
      a0 = fmaf(wv0.x, h2[c], a0); a0 = fmaf(wv0.y, h2[c+1], a0); a0 = fmaf(wv0.z, h2[c+2], a0); a0 = fmaf(wv0.w, h2[c+3], a0);
      a1 = fmaf(wv1.x, h2[c], a1); a1 = fmaf(wv1.y, h2[c+1], a1); a1 = fmaf(wv1.z, h2[c+2], a1); a1 = fmaf(wv1.w, h2[c+3], a1);
      a2 = fmaf(wv2.x, h2[c], a2); a2 = fmaf(wv2.y, h2[c+1], a2); a2 = fmaf(wv2.z, h2[c+2], a2); a2 = fmaf(wv2.w, h2[c+3], a2);
      a3 = fmaf(wv3.x, h2[c], a3); a3 = fmaf(wv3.y, h2[c+1], a3); a3 = fmaf(wv3.z, h2[c+2], a3); a3 = fmaf(wv3.w, h2[c+3], a3);
    }
    float4 ov;
    ov.x = fmaxf(fmaf(a0, S->ss2[o    ], S->ee2[o    ]), 0.0f);
    ov.y = fmaxf(fmaf(a1, S->ss2[o + 1], S->ee2[o + 1]), 0.0f);
    ov.z = fmaxf(fmaf(a2, S->ss2[o + 2], S->ee2[o + 2]), 0.0f);
    ov.w = fmaxf(fmaf(a3, S->ss2[o + 3], S->ee2[o + 3]), 0.0f);
    *(float4*)(orow + o) = ov;
  }
}

__global__ __launch_bounds__(256) void f1_kernel(const float* __restrict__ pts,
    const float* __restrict__ W0, const float* __restrict__ B0, const float* __restrict__ G0, const float* __restrict__ E0,
    const float* __restrict__ W1, const float* __restrict__ B1, const float* __restrict__ G1, const float* __restrict__ E1,
    const float* __restrict__ W2, const float* __restrict__ B2, const float* __restrict__ G2, const float* __restrict__ E2,
    float* __restrict__ mfeat, int* __restrict__ cidx,
    float* __restrict__ X, float* __restrict__ Y, float* __restrict__ Z) {
  __shared__ __align__(16) char smem[F1_SMEM];
  if (blockIdx.x < 8)
    fps_body(smem, pts, cidx, X, Y, Z);
  else
    mlp_body(smem, pts, W0, B0, G0, E0, W1, B1, G1, E1, W2, B2, G2, E2, mfeat);
}

// ---------------------------------------------------------------------------
// F2: fused ball-query (blocks 0..2047) + attention projection P = [xyz,f]@A
// (blocks 2048..2303). Independent given F1's outputs.
// ---------------------------------------------------------------------------
// Ball query: one wave per center. Exact f32 replication of
// d = ((-2*dot)+sc)+sx, mask d>0.04f, stable-(d,idx) 32-smallest, pad w/ first.
// Extraction uses u64 (mapped-d, idx) keys + VALU-only DPP min ladder: no
// DS-pipe swizzles on the 32-iteration dependent chain.
__device__ void ballq_body(const float* __restrict__ X, const float* __restrict__ Y,
                           const float* __restrict__ Z, const int* __restrict__ cidx,
                           int* __restrict__ gidx,
                           float (*dbuf)[512], int (*ibuf)[512]) {
  const int t = threadIdx.x;
  const int w = t >> 6, lane = t & 63;
  const int pc = blockIdx.x * 4 + w;               // 0..8191
  const int b = pc >> 10;
  const float* Xb = X + b * NPTS;
  const float* Yb = Y + b * NPTS;
  const float* Zb = Z + b * NPTS;
  const int cI = cidx[pc];
  const float cx = Xb[cI], cy = Yb[cI], cz = Zb[cI];
  const float sc = __fadd_rn(__fadd_rn(__fmul_rn(cx, cx), __fmul_rn(cy, cy)), __fmul_rn(cz, cz));
  const float R2 = 0.04f;
  int cnt = 0;                                     // wave-uniform
  for (int rr = 0; rr < 64; rr++) {
    int nI = rr * 64 + lane;
    float px = Xb[nI], py = Yb[nI], pz = Zb[nI];
    float dot = __fadd_rn(__fadd_rn(__fmul_rn(cx, px), __fmul_rn(cy, py)), __fmul_rn(cz, pz));
    float sx  = __fadd_rn(__fadd_rn(__fmul_rn(px, px), __fmul_rn(py, py)), __fmul_rn(pz, pz));
    float d   = __fadd_rn(__fadd_rn(__fmul_rn(-2.0f, dot), sc), sx);
    bool pred = !(d > R2);
    unsigned long long mask = __ballot(pred);
    if (pred) {
      int pos = cnt + (int)__popcll(mask & ((1ull << lane) - 1ull));
      if (pos < 512) { dbuf[w][pos] = d; ibuf[w][pos] = nI; }
    }
    cnt += (int)__popcll(mask);
  }
  const int K = cnt < 512 ? cnt : 512;
  // u64 keys: hi = monotone-mapped d, lo = idx  ->  min key = (d,idx)-lex min
  unsigned long long kk[8];
  #pragma unroll
  for (int k = 0; k < 8; k++) {
    int pos = lane + 64 * k;
    if (pos < K)
      kk[k] = ((unsigned long long)fmap(dbuf[w][pos]) << 32) | (unsigned)ibuf[w][pos];
    else
      kk[k] = ((unsigned long long)FMAP_INF << 32) | 0x7fffffffu;
  }
  int first = 0;
  int* gout = gidx + pc * NSAMPLE;
  for (int it = 0; it < NSAMPLE; it++) {
    unsigned long long best = kk[0];
    #pragma unroll
    for (int k = 1; k < 8; k++) if (kk[k] < best) best = kk[k];
    unsigned hi = (unsigned)(best >> 32), lo = (unsigned)best;
    dpp_min2<DPP_QUAD_XOR1>(hi, lo);
    dpp_min2<DPP_QUAD_XOR2>(hi, lo);
    dpp_min2<DPP_ROW_HALF_MIRROR>(hi, lo);
    dpp_min2<DPP_ROW_MIRROR>(hi, lo);
    dpp_min2<DPP_ROW_BCAST15>(hi, lo);
    dpp_min2<DPP_ROW_BCAST31>(hi, lo);             // lane63 = wave min
    unsigned blo = (unsigned)__builtin_amdgcn_readlane((int)lo, 63);
    // remove: set d to +INF, keep idx (indices unique among valid entries)
    #pragma unroll
    for (int k = 0; k < 8; k++)
      if ((unsigned)kk[k] == blo)
        kk[k] = (kk[k] & 0xFFFFFFFFull) | ((unsigned long long)FMAP_INF << 32);
    if (it == 0) first = (int)blo;
    if (lane == 0) gout[it] = (it < K) ? (int)blo : first;
  }
}

// P projection: block = (row-tile of 512) x (col-group of 32). Each thread
// computes 2 rows x 32 cols; A col-slice staged in LDS (broadcast b128 reads).
__device__ void proj_body(const float* __restrict__ X, const float* __restrict__ Y,
                          const float* __restrict__ Z, const float* __restrict__ mfeat,
                          const float* __restrict__ Aatt, float* __restrict__ P,
                          float* As /* [131*32] */) {
  const int t = threadIdx.x;
  const int pb = blockIdx.x - 2048;                // 0..255
  const int grp = pb & 3;                          // col group: cols grp*32..+32
  const int tile = pb >> 2;                        // 0..63 -> rows tile*512..+512
  for (int i = t; i < 131 * 32; i += 256) {
    int c = i >> 5, col = i & 31;
    As[i] = Aatt[c * 128 + grp * 32 + col];
  }
  __syncthreads();
  const int r0 = tile * 512 + t * 2;               // rows r0, r0+1
  float acc0[32], acc1[32];
  {
    float x0 = X[r0], y0 = Y[r0], z0 = Z[r0];
    float x1 = X[r0 + 1], y1 = Y[r0 + 1], z1 = Z[r0 + 1];
    #pragma unroll
    for (int j = 0; j < 32; j += 4) {
      float4 a0 = *(const float4*)&As[0 * 32 + j];
      float4 a1 = *(const float4*)&As[1 * 32 + j];
      float4 a2 = *(const float4*)&As[2 * 32 + j];
      acc0[j]   = fmaf(z0, a2.x, fmaf(y0, a1.x, x0 * a0.x));
      acc0[j+1] = fmaf(z0, a2.y, fmaf(y0, a1.y, x0 * a0.y));
      acc0[j+2] = fmaf(z0, a2.z, fmaf(y0, a1.z, x0 * a0.z));
      acc0[j+3] = fmaf(z0, a2.w, fmaf(y0, a1.w, x0 * a0.w));
      acc1[j]   = fmaf(z1, a2.x, fmaf(y1, a1.x, x1 * a0.x));
      acc1[j+1] = fmaf(z1, a2.y, fmaf(y1, a1.y, x1 * a0.y));
      acc1[j+2] = fmaf(z1, a2.z, fmaf(y1, a1.z, x1 * a0.z));
      acc1[j+3] = fmaf(z1, a2.w, fmaf(y1, a1.w, x1 * a0.w));
    }
  }
  const float* m0 = mfeat + (size_t)r0 * 128;
  const float* m1 = m0 + 128;
  for (int c = 0; c < 128; c += 4) {
    float4 v0 = *(const float4*)(m0 + c);
    float4 v1 = *(const float4*)(m1 + c);
    #pragma unroll
    for (int u = 0; u < 4; u++) {
      const float* arow = &As[(3 + c + u) * 32];
      float s0 = u == 0 ? v0.x : u == 1 ? v0.y : u == 2 ? v0.z : v0.w;
      float s1 = u == 0 ? v1.x : u == 1 ? v1.y : u == 2 ? v1.z : v1.w;
      #pragma unroll
      for (int j = 0; j < 32; j += 4) {
        float4 a = *(const float4*)&arow[j];
        acc0[j]   = fmaf(s0, a.x, acc0[j]);
        acc0[j+1] = fmaf(s0, a.y, acc0[j+1]);
        acc0[j+2] = fmaf(s0, a.z, acc0[j+2]);
        acc0[j+3] = fmaf(s0, a.w, acc0[j+3]);
        acc1[j]   = fmaf(s1, a.x, acc1[j]);
        acc1[j+1] = fmaf(s1, a.y, acc1[j+1]);
        acc1[j+2] = fmaf(s1, a.z, acc1[j+2]);
        acc1[j+3] = fmaf(s1, a.w, acc1[j+3]);
      }
    }
  }
  float* p0 = P + (size_t)r0 * 128 + grp * 32;
  float* p1 = p0 + 128;
  #pragma unroll
  for (int j = 0; j < 32; j += 4) {
    *(float4*)(p0 + j) = make_float4(acc0[j], acc0[j+1], acc0[j+2], acc0[j+3]);
    *(float4*)(p1 + j) = make_float4(acc1[j], acc1[j+1], acc1[j+2], acc1[j+3]);
  }
}

__global__ __launch_bounds__(256) void f2_kernel(
    const float* __restrict__ X, const float* __restrict__ Y, const float* __restrict__ Z,
    const int* __restrict__ cidx, int* __restrict__ gidx,
    const float* __restrict__ mfeat, const float* __restrict__ Aatt,
    float* __restrict__ P) {
  __shared__ float dbuf[4][512];
  __shared__ int   ibuf[4][512];
  __shared__ float As[131 * 32];
  if (blockIdx.x < 2048)
    ballq_body(X, Y, Z, cidx, gidx, dbuf, ibuf);
  else
    proj_body(X, Y, Z, mfeat, Aatt, P, As);
}

// ---------------------------------------------------------------------------
// F3: attention-lite. logits = P[g] - P[c] (projection identity), leaky,
// softmax over n via 32-lane shuffles, weighted gfeat sum. Zero LDS; block
// per center; XCD-swizzled so each batch's P/mfeat slice stays in one L2.
// ---------------------------------------------------------------------------
__global__ __launch_bounds__(256) void attn_kernel(
    const float* __restrict__ X, const float* __restrict__ Y, const float* __restrict__ Z,
    const float* __restrict__ mfeat, const float* __restrict__ P,
    const int* __restrict__ cidx, const int* __restrict__ gidx,
    float* __restrict__ out) {
  const int pc = (blockIdx.x & 7) * 1024 + (blockIdx.x >> 3);  // batch-per-XCD
  const int b = pc >> 10;
  const int t = threadIdx.x;
  const int n = t & 31, q = t >> 5;                // q: 0..7, 16 channels each
  const int cI = cidx[pc];
  const int g = gidx[pc * NSAMPLE + n];
  const float* Pg = P + ((size_t)b * NPTS + g) * 128 + q * 16;
  const float* Pc = P + ((size_t)b * NPTS + cI) * 128 + q * 16;
  const float* Gf = mfeat + ((size_t)b * NPTS + g) * 128 + q * 16;
  float a[16], gfv[16];
  #pragma unroll
  for (int k = 0; k < 4; k++) {
    float4 vg = *(const float4*)(Pg + 4 * k);
    float4 vc = *(const float4*)(Pc + 4 * k);
    float4 vf = *(const float4*)(Gf + 4 * k);
    a[4*k]   = vg.x - vc.x; a[4*k+1] = vg.y - vc.y;
    a[4*k+2] = vg.z - vc.z; a[4*k+3] = vg.w - vc.w;
    gfv[4*k] = vf.x; gfv[4*k+1] = vf.y; gfv[4*k+2] = vf.z; gfv[4*k+3] = vf.w;
  }
  #pragma unroll
  for (int j = 0; j < 16; j++) a[j] = a[j] >= 0.0f ? a[j] : 0.2f * a[j];
  // softmax over n (32-lane subgroup; xor offsets <32 stay in group)
  float mx[16];
  #pragma unroll
  for (int j = 0; j < 16; j++) mx[j] = a[j];
  #pragma unroll
  for (int off = 16; off >= 1; off >>= 1)
    #pragma unroll
    for (int j = 0; j < 16; j++) mx[j] = fmaxf(mx[j], __shfl_xor(mx[j], off));
  float e[16], s[16];
  #pragma unroll
  for (int j = 0; j < 16; j++) { e[j] = expf(a[j] - mx[j]); s[j] = e[j]; }
  #pragma unroll
  for (int off = 16; off >= 1; off >>= 1)
    #pragma unroll
    for (int j = 0; j < 16; j++) s[j] += __shfl_xor(s[j], off);
  float gac[16];
  #pragma unroll
  for (int j = 0; j < 16; j++) gac[j] = (e[j] / s[j]) * gfv[j];
  #pragma unroll
  for (int off = 16; off >= 1; off >>= 1)
    #pragma unroll
    for (int j = 0; j < 16; j++) gac[j] += __shfl_xor(gac[j], off);
  if (n == 0) {
    float* orow = out + (size_t)pc * 131;
    #pragma unroll
    for (int j = 0; j < 16; j++) orow[3 + q * 16 + j] = gac[j];
    if (q == 0) {
      orow[0] = X[b * NPTS + cI]; orow[1] = Y[b * NPTS + cI]; orow[2] = Z[b * NPTS + cI];
    }
  }
}

// ---------------------------------------------------------------------------
extern "C" void kernel_launch(void* const* d_in, const int* in_sizes, int n_in,
                              void* d_out, int out_size, void* d_ws, size_t ws_size,
                              hipStream_t stream) {
  const float* points = (const float*)d_in[0];
  const float* W0 = (const float*)d_in[1];
  const float* B0 = (const float*)d_in[2];
  const float* G0 = (const float*)d_in[3];
  const float* E0 = (const float*)d_in[4];
  const float* W1 = (const float*)d_in[5];
  const float* B1 = (const float*)d_in[6];
  const float* G1 = (const float*)d_in[7];
  const float* E1 = (const float*)d_in[8];
  const float* W2 = (const float*)d_in[9];
  const float* B2 = (const float*)d_in[10];
  const float* G2 = (const float*)d_in[11];
  const float* E2 = (const float*)d_in[12];
  const float* Aatt = (const float*)d_in[13];
  float* out = (float*)d_out;

  // workspace (floats): mfeat 4.19M | P 4.19M | X/Y/Z 3*32k | cidx 8k | gidx 256k  (~35 MB)
  float* mfeat = (float*)d_ws;
  float* Pw = mfeat + (size_t)NBATCH * NPTS * 128;
  float* Xw = Pw + (size_t)NBATCH * NPTS * 128;
  float* Yw = Xw + NBATCH * NPTS;
  float* Zw = Yw + NBATCH * NPTS;
  int* cidxw = (int*)(Zw + NBATCH * NPTS);
  int* gidxw = cidxw + NBATCH * NPOINT;

  f1_kernel<<<8 + NBATCH * NPTS / 256, 256, 0, stream>>>(points,
      W0, B0, G0, E0, W1, B1, G1, E1, W2, B2, G2, E2, mfeat, cidxw, Xw, Yw, Zw);
  f2_kernel<<<2048 + 256, 256, 0, stream>>>(Xw, Yw, Zw, cidxw, gidxw, mfeat, Aatt, Pw);
  attn_kernel<<<NBATCH * NPOINT, 256, 0, stream>>>(Xw, Yw, Zw, mfeat, Pw, cidxw, gidxw, out);
}

// Round 7
// 897.311 us; speedup vs baseline: 1.2061x; 1.2061x over previous
//
#include <hip/hip_runtime.h>
#include <math.h>

#define NBATCH 8
#define NPTS 4096
#define NPOINT 1024
#define NSAMPLE 32
#define PTDIM 67        // 3 xyz + 64 feat
#define BIGF 1e10f

// DPP ctrl encodings (gfx9/CDNA)
#define DPP_QUAD_XOR1 0xB1   // quad_perm [1,0,3,2]
#define DPP_QUAD_XOR2 0x4E   // quad_perm [2,3,0,1]
#define DPP_ROW_HALF_MIRROR 0x141
#define DPP_ROW_MIRROR 0x140
#define DPP_ROW_BCAST15 0x142
#define DPP_ROW_BCAST31 0x143

// self-as-old DPP moves: un-sourced lanes keep self -> combine is a no-op there
template <int CTRL>
__device__ inline float dpp_mov_f(float v) {
  int i = __float_as_int(v);
  return __int_as_float(__builtin_amdgcn_update_dpp(i, i, CTRL, 0xf, 0xf, false));
}
template <int CTRL>
__device__ inline unsigned dpp_mov_u(unsigned v) {
  return (unsigned)__builtin_amdgcn_update_dpp((int)v, (int)v, CTRL, 0xf, 0xf, false);
}
// lexicographic u64 (hi,lo) min combine over a DPP pattern (VALU-only)
template <int CTRL>
__device__ inline void dpp_min2(unsigned& hi, unsigned& lo) {
  unsigned nh = dpp_mov_u<CTRL>(hi);
  unsigned nl = dpp_mov_u<CTRL>(lo);
  bool take = (nh < hi) || (nh == hi && nl < lo);
  hi = take ? nh : hi;
  lo = take ? nl : lo;
}
// monotone map f32 -> u32 (ascending order preserved, incl. negatives)
__device__ inline unsigned fmap(float d) {
  unsigned b = __float_as_uint(d);
  return ((int)b < 0) ? ~b : (b | 0x80000000u);
}
#define FMAP_INF 0xFF800000u   // fmap(+INF)

// 32-lane-group reductions: 4 VALU-DPP levels + ONE DS op (xor16) per value.
// (patterns merge {xor1, xor2, 8-block, 16-row}; every lane ends with the
// 32-group total — verified pattern coverage in comments at each step)
__device__ inline float red32_max(float v) {
  v = fmaxf(v, dpp_mov_f<DPP_QUAD_XOR1>(v));        // pair sums
  v = fmaxf(v, dpp_mov_f<DPP_QUAD_XOR2>(v));        // quad
  v = fmaxf(v, dpp_mov_f<DPP_ROW_HALF_MIRROR>(v));  // 8-block (7-i pairs quads)
  v = fmaxf(v, dpp_mov_f<DPP_ROW_MIRROR>(v));       // 16-row
  v = fmaxf(v, __shfl_xor(v, 16));                  // 32-group
  return v;
}
__device__ inline float red32_sum(float v) {
  v += dpp_mov_f<DPP_QUAD_XOR1>(v);
  v += dpp_mov_f<DPP_QUAD_XOR2>(v);
  v += dpp_mov_f<DPP_ROW_HALF_MIRROR>(v);
  v += dpp_mov_f<DPP_ROW_MIRROR>(v);
  v += __shfl_xor(v, 16);
  return v;
}

// ---------------------------------------------------------------------------
// F1: fused FPS (blocks 0..7; also emits SoA xyz) + MLP (blocks 8..135).
// LDS overlaid via char buffer.
// ---------------------------------------------------------------------------
struct FpsS {
  unsigned long long slots[2][4];
  int cidxS[NPOINT];
  float4 C[NPTS];                                  // packed coords: 1 b128/lookup
};
struct MlpS {
  float w0[64 * 64], w1[64 * 64], w2[128 * 64];
  float bb0[64], ss0[64], ee0[64];
  float bb1[64], ss1[64], ee1[64];
  float bb2[128], ss2[128], ee2[128];
};
#define F1_SMEM (sizeof(MlpS) > sizeof(FpsS) ? sizeof(MlpS) : sizeof(FpsS))

// FPS: one block per batch, 256 thr, 16 pts/lane in VGPRs. R5 structure
// (s_barrier via __syncthreads — R6's LDS-spin experiment REGRESSED, keep the
// barrier). Per-lane argmax restructured as trees: fmaxf tree (depth 4) ->
// DPP max ladder -> readlane63 -> qualify (bit-equal, exact: sums of squares
// never -0) -> min-j tree -> DPP min ladder -> readlane63. 4 cross-wave u64
// slots + ONE barrier/step; coords via single ds_read_b128.
// Exact f32 replication of jnp: ((dx*dx+dy*dy)+dz*dz), min, argmax first-idx.
__device__ void fps_body(char* smemRaw, const float* __restrict__ pts,
                         int* __restrict__ cidx, float* __restrict__ X,
                         float* __restrict__ Y, float* __restrict__ Z) {
  FpsS* S = (FpsS*)smemRaw;
  const int b = blockIdx.x, tid = threadIdx.x;
  const int w = tid >> 6, lane = tid & 63;
  const float* pb = pts + (size_t)b * NPTS * PTDIM;
  float px[16], py[16], pz[16], dl[16];
  #pragma unroll
  for (int k = 0; k < 16; k++) {
    int j = tid + (k << 8);
    const float* pj = pb + (size_t)j * PTDIM;
    float x = pj[0], y = pj[1], z = pj[2];
    px[k] = x; py[k] = y; pz[k] = z;
    S->C[j] = make_float4(x, y, z, 0.0f);
    X[b * NPTS + j] = x; Y[b * NPTS + j] = y; Z[b * NPTS + j] = z;  // SoA out
    dl[k] = BIGF;
  }
  __syncthreads();
  int f = 0;
  float4 c0 = S->C[0];
  float cx = c0.x, cy = c0.y, cz = c0.z;
  for (int t = 0; t < NPOINT; t++) {
    if (tid == 0) S->cidxS[t] = f;                 // emit BEFORE update
    #pragma unroll
    for (int k = 0; k < 16; k++) {
      float dx = __fsub_rn(px[k], cx);
      float dy = __fsub_rn(py[k], cy);
      float dz = __fsub_rn(pz[k], cz);
      float d = __fadd_rn(__fadd_rn(__fmul_rn(dx, dx), __fmul_rn(dy, dy)), __fmul_rn(dz, dz));
      dl[k] = fminf(dl[k], d);
    }
    // per-lane max via tree (depth 4, independent ops)
    float u0 = fmaxf(dl[0], dl[1]),  u1 = fmaxf(dl[2], dl[3]);
    float u2 = fmaxf(dl[4], dl[5]),  u3 = fmaxf(dl[6], dl[7]);
    float u4 = fmaxf(dl[8], dl[9]),  u5 = fmaxf(dl[10], dl[11]);
    float u6 = fmaxf(dl[12], dl[13]), u7 = fmaxf(dl[14], dl[15]);
    float v0 = fmaxf(u0, u1), v1 = fmaxf(u2, u3);
    float v2 = fmaxf(u4, u5), v3 = fmaxf(u6, u7);
    float bv = fmaxf(fmaxf(v0, v1), fmaxf(v2, v3));
    // phase 1: wave max (2 instr/level, VALU-only)
    float m = bv;
    m = fmaxf(m, dpp_mov_f<DPP_QUAD_XOR1>(m));
    m = fmaxf(m, dpp_mov_f<DPP_QUAD_XOR2>(m));
    m = fmaxf(m, dpp_mov_f<DPP_ROW_HALF_MIRROR>(m));
    m = fmaxf(m, dpp_mov_f<DPP_ROW_MIRROR>(m));
    m = fmaxf(m, dpp_mov_f<DPP_ROW_BCAST15>(m));
    m = fmaxf(m, dpp_mov_f<DPP_ROW_BCAST31>(m));   // lane63 = wave max
    unsigned wmaxbits = (unsigned)__builtin_amdgcn_readlane(__float_as_int(m), 63);
    // phase 2: min index among (lane,k) holding the max — qualify + trees
    unsigned c_[16];
    #pragma unroll
    for (int k = 0; k < 16; k++)
      c_[k] = (__float_as_uint(dl[k]) == wmaxbits) ? (unsigned)(tid + (k << 8)) : 0xFFFFFFFFu;
    unsigned q0 = min(c_[0], c_[1]),  q1 = min(c_[2], c_[3]);
    unsigned q2 = min(c_[4], c_[5]),  q3 = min(c_[6], c_[7]);
    unsigned q4 = min(c_[8], c_[9]),  q5 = min(c_[10], c_[11]);
    unsigned q6 = min(c_[12], c_[13]), q7 = min(c_[14], c_[15]);
    unsigned r0 = min(q0, q1), r1 = min(q2, q3), r2 = min(q4, q5), r3 = min(q6, q7);
    unsigned cand = min(min(r0, r1), min(r2, r3));
    cand = min(cand, dpp_mov_u<DPP_QUAD_XOR1>(cand));
    cand = min(cand, dpp_mov_u<DPP_QUAD_XOR2>(cand));
    cand = min(cand, dpp_mov_u<DPP_ROW_HALF_MIRROR>(cand));
    cand = min(cand, dpp_mov_u<DPP_ROW_MIRROR>(cand));
    cand = min(cand, dpp_mov_u<DPP_ROW_BCAST15>(cand));
    cand = min(cand, dpp_mov_u<DPP_ROW_BCAST31>(cand));  // lane63 = min j
    unsigned jmin = (unsigned)__builtin_amdgcn_readlane((int)cand, 63);
    if (lane == 0)
      S->slots[t & 1][w] = ((unsigned long long)wmaxbits << 32) |
                           (unsigned long long)(NPTS - 1 - jmin);  // bigger = smaller idx
    __syncthreads();
    unsigned long long s0 = S->slots[t & 1][0], s1 = S->slots[t & 1][1];
    unsigned long long s2 = S->slots[t & 1][2], s3 = S->slots[t & 1][3];
    unsigned long long m0 = s0 > s1 ? s0 : s1;
    unsigned long long m1 = s2 > s3 ? s2 : s3;
    unsigned long long best = m0 > m1 ? m0 : m1;
    f = NPTS - 1 - (int)(best & 0xFFFFFFFFull);
    float4 cc = S->C[f];                           // ONE b128 same-addr broadcast
    cx = cc.x; cy = cc.y; cz = cc.z;
  }
  __syncthreads();
  for (int i = tid; i < NPOINT; i += 256) cidx[b * NPOINT + i] = S->cidxS[i];
}

// MLP over ALL points (MLP∘gather == gather∘MLP). Thread-per-row, weights in
// LDS (broadcast reads), fully unrolled so x/h stay in VGPRs.
__device__ void mlp_body(char* smemRaw, const float* __restrict__ pts,
    const float* __restrict__ W0, const float* __restrict__ B0, const float* __restrict__ G0, const float* __restrict__ E0,
    const float* __restrict__ W1, const float* __restrict__ B1, const float* __restrict__ G1, const float* __restrict__ E1,
    const float* __restrict__ W2, const float* __restrict__ B2, const float* __restrict__ G2, const float* __restrict__ E2,
    float* __restrict__ mfeat) {
  MlpS* S = (MlpS*)smemRaw;
  const float INVS = 0.99999500003750f;            // 1/sqrt(1+1e-5)
  const int t = threadIdx.x;
  for (int i = t; i < 4096; i += 256) { S->w0[i] = W0[i]; S->w1[i] = W1[i]; }
  for (int i = t; i < 8192; i += 256) { S->w2[i] = W2[i]; }
  if (t < 64) {
    S->bb0[t] = B0[t]; S->ss0[t] = G0[t] * INVS; S->ee0[t] = E0[t];
    S->bb1[t] = B1[t]; S->ss1[t] = G1[t] * INVS; S->ee1[t] = E1[t];
  }
  if (t < 128) { S->bb2[t] = B2[t]; S->ss2[t] = G2[t] * INVS; S->ee2[t] = E2[t]; }
  __syncthreads();

  const size_t r = (size_t)(blockIdx.x - 8) * 256 + t;   // row 0..32767
  const float* xr = pts + r * PTDIM + 3;
  float x[64];
  #pragma unroll
  for (int c = 0; c < 64; c++) x[c] = xr[c];

  float h1[64];
  #pragma unroll
  for (int o = 0; o < 64; o++) {
    float acc = S->bb0[o];
    #pragma unroll
    for (int c = 0; c < 64; c += 4) {
      float4 wv = *(const float4*)&S->w0[o * 64 + c];
      acc = fmaf(wv.x, x[c], acc);
      acc = fmaf(wv.y, x[c + 1], acc);
      acc = fmaf(wv.z, x[c + 2], acc);
      acc = fmaf(wv.w, x[c + 3], acc);
    }
    h1[o] = fmaxf(fmaf(acc, S->ss0[o], S->ee0[o]), 0.0f);
  }
  float h2[64];
  #pragma unroll
  for (int o = 0; o < 64; o++) {
    float acc = S->bb1[o];
    #pragma unroll
    for (int c = 0; c < 64; c += 4) {
      float4 wv = *(const float4*)&S->w1[o * 64 + c];
      acc = fmaf(wv.x, h1[c], acc);
      acc = fmaf(wv.y, h1[c + 1], acc);
      acc = fmaf(wv.z, h1[c + 2], acc);
      acc = fmaf(wv.w, h1[c + 3], acc);
    }
    h2[o] = fmaxf(fmaf(acc, S->ss1[o], S->ee1[o]), 0.0f);
  }
  float* orow = mfeat + r * 128;
  #pragma unroll
  for (int o = 0; o < 128; o += 4) {
    float a0 = S->bb2[o], a1 = S->bb2[o + 1], a2 = S->bb2[o + 2], a3 = S->bb2[o + 3];
    #pragma unroll
    for (int c = 0; c < 64; c += 4) {
      float4 wv0 = *(const float4*)&S->w2[(o    ) * 64 + c];
      float4 wv1 = *(const float4*)&S->w2[(o + 1) * 64 + c];
      float4 wv2 = *(const float4*)&S->w2[(o + 2) * 64 + c];
      float4 wv3 = *(const float4*)&S->w2[(o + 3) * 64 + c];
      a0 = fmaf(wv0.x, h2[c], a0); a0 = fmaf(wv0.y, h2[c+1], a0); a0 = fmaf(wv0.z, h2[c+2], a0); a0 = fmaf(wv0.w, h2[c+3], a0);
      a1 = fmaf(wv1.x, h2[c], a1); a1 = fmaf(wv1.y, h2[c+1], a1); a1 = fmaf(wv1.z, h2[c+2], a1); a1 = fmaf(wv1.w, h2[c+3], a1);
      a2 = fmaf(wv2.x, h2[c], a2); a2 = fmaf(wv2.y, h2[c+1], a2); a2 = fmaf(wv2.z, h2[c+2], a2); a2 = fmaf(wv2.w, h2[c+3], a2);
      a3 = fmaf(wv3.x, h2[c], a3); a3 = fmaf(wv3.y, h2[c+1], a3); a3 = fmaf(wv3.z, h2[c+2], a3); a3 = fmaf(wv3.w, h2[c+3], a3);
    }
    float4 ov;
    ov.x = fmaxf(fmaf(a0, S->ss2[o    ], S->ee2[o    ]), 0.0f);
    ov.y = fmaxf(fmaf(a1, S->ss2[o + 1], S->ee2[o + 1]), 0.0f);
    ov.z = fmaxf(fmaf(a2, S->ss2[o + 2], S->ee2[o + 2]), 0.0f);
    ov.w = fmaxf(fmaf(a3, S->ss2[o + 3], S->ee2[o + 3]), 0.0f);
    *(float4*)(orow + o) = ov;
  }
}

__global__ __launch_bounds__(256) void f1_kernel(const float* __restrict__ pts,
    const float* __restrict__ W0, const float* __restrict__ B0, const float* __restrict__ G0, const float* __restrict__ E0,
    const float* __restrict__ W1, const float* __restrict__ B1, const float* __restrict__ G1, const float* __restrict__ E1,
    const float* __restrict__ W2, const float* __restrict__ B2, const float* __restrict__ G2, const float* __restrict__ E2,
    float* __restrict__ mfeat, int* __restrict__ cidx,
    float* __restrict__ X, float* __restrict__ Y, float* __restrict__ Z) {
  __shared__ __align__(16) char smem[F1_SMEM];
  if (blockIdx.x < 8)
    fps_body(smem, pts, cidx, X, Y, Z);
  else
    mlp_body(smem, pts, W0, B0, G0, E0, W1, B1, G1, E1, W2, B2, G2, E2, mfeat);
}

// ---------------------------------------------------------------------------
// F2: fused ball-query (blocks 0..2047) + attention projection P = [xyz,f]@A
// (blocks 2048..2303). LDS UNIONED (ballq 16.4 KB / proj 16.8 KB -> 16.8 KB
// block, 8 blocks/CU vs 4 before).
// ---------------------------------------------------------------------------
#define F2_SMEM 16768

// Ball query: one wave per center. Exact f32 replication of
// d = ((-2*dot)+sc)+sx, mask d>0.04f, stable-(d,idx) 32-smallest, pad w/first.
// Scan uses float4 loads (48 VMEM instrs vs 192); compaction order across the
// 4 sub-elements is interleaved but irrelevant — selection keys on (d, true
// index), and the 512 cap is ~27 sigma above the ~137 expected candidates.
__device__ void ballq_body(char* smemRaw,
                           const float* __restrict__ X, const float* __restrict__ Y,
                           const float* __restrict__ Z, const int* __restrict__ cidx,
                           int* __restrict__ gidx) {
  float (*dbuf)[512] = (float (*)[512])smemRaw;
  int   (*ibuf)[512] = (int (*)[512])(smemRaw + 4 * 512 * 4);
  const int t = threadIdx.x;
  const int w = t >> 6, lane = t & 63;
  const int pc = blockIdx.x * 4 + w;               // 0..8191
  const int b = pc >> 10;
  const float* Xb = X + b * NPTS;
  const float* Yb = Y + b * NPTS;
  const float* Zb = Z + b * NPTS;
  const int cI = cidx[pc];
  const float cx = Xb[cI], cy = Yb[cI], cz = Zb[cI];
  const float sc = __fadd_rn(__fadd_rn(__fmul_rn(cx, cx), __fmul_rn(cy, cy)), __fmul_rn(cz, cz));
  const float R2 = 0.04f;
  int cnt = 0;                                     // wave-uniform
  for (int rr = 0; rr < 16; rr++) {
    const int base = rr * 256 + lane * 4;
    float4 px4 = *(const float4*)(Xb + base);
    float4 py4 = *(const float4*)(Yb + base);
    float4 pz4 = *(const float4*)(Zb + base);
    #pragma unroll
    for (int e = 0; e < 4; e++) {
      float px = e == 0 ? px4.x : e == 1 ? px4.y : e == 2 ? px4.z : px4.w;
      float py = e == 0 ? py4.x : e == 1 ? py4.y : e == 2 ? py4.z : py4.w;
      float pz = e == 0 ? pz4.x : e == 1 ? pz4.y : e == 2 ? pz4.z : pz4.w;
      float dot = __fadd_rn(__fadd_rn(__fmul_rn(cx, px), __fmul_rn(cy, py)), __fmul_rn(cz, pz));
      float sx  = __fadd_rn(__fadd_rn(__fmul_rn(px, px), __fmul_rn(py, py)), __fmul_rn(pz, pz));
      float d   = __fadd_rn(__fadd_rn(__fmul_rn(-2.0f, dot), sc), sx);
      bool pred = !(d > R2);
      unsigned long long mask = __ballot(pred);
      if (pred) {
        int pos = cnt + (int)__popcll(mask & ((1ull << lane) - 1ull));
        if (pos < 512) { dbuf[w][pos] = d; ibuf[w][pos] = base + e; }
      }
      cnt += (int)__popcll(mask);
    }
  }
  const int K = cnt < 512 ? cnt : 512;
  // u64 keys: hi = monotone-mapped d, lo = idx  ->  min key = (d,idx)-lex min
  unsigned long long kk[8];
  #pragma unroll
  for (int k = 0; k < 8; k++) {
    int pos = lane + 64 * k;
    if (pos < K)
      kk[k] = ((unsigned long long)fmap(dbuf[w][pos]) << 32) | (unsigned)ibuf[w][pos];
    else
      kk[k] = ((unsigned long long)FMAP_INF << 32) | 0x7fffffffu;
  }
  int first = 0;
  int* gout = gidx + pc * NSAMPLE;
  for (int it = 0; it < NSAMPLE; it++) {
    unsigned long long best = kk[0];
    #pragma unroll
    for (int k = 1; k < 8; k++) if (kk[k] < best) best = kk[k];
    unsigned hi = (unsigned)(best >> 32), lo = (unsigned)best;
    dpp_min2<DPP_QUAD_XOR1>(hi, lo);
    dpp_min2<DPP_QUAD_XOR2>(hi, lo);
    dpp_min2<DPP_ROW_HALF_MIRROR>(hi, lo);
    dpp_min2<DPP_ROW_MIRROR>(hi, lo);
    dpp_min2<DPP_ROW_BCAST15>(hi, lo);
    dpp_min2<DPP_ROW_BCAST31>(hi, lo);             // lane63 = wave min
    unsigned blo = (unsigned)__builtin_amdgcn_readlane((int)lo, 63);
    // remove: set d to +INF, keep idx (indices unique among valid entries)
    #pragma unroll
    for (int k = 0; k < 8; k++)
      if ((unsigned)kk[k] == blo)
        kk[k] = (kk[k] & 0xFFFFFFFFull) | ((unsigned long long)FMAP_INF << 32);
    if (it == 0) first = (int)blo;
    if (lane == 0) gout[it] = (it < K) ? (int)blo : first;
  }
}

// P projection: block = (row-tile of 512) x (col-group of 32). Each thread
// computes 2 rows x 32 cols; A col-slice staged in LDS (broadcast b128 reads).
__device__ void proj_body(char* smemRaw,
                          const float* __restrict__ X, const float* __restrict__ Y,
                          const float* __restrict__ Z, const float* __restrict__ mfeat,
                          const float* __restrict__ Aatt, float* __restrict__ P) {
  float* As = (float*)smemRaw;                     // [131*32]
  const int t = threadIdx.x;
  const int pb = blockIdx.x - 2048;                // 0..255
  const int grp = pb & 3;                          // col group: cols grp*32..+32
  const int tile = pb >> 2;                        // 0..63 -> rows tile*512..+512
  for (int i = t; i < 131 * 32; i += 256) {
    int c = i >> 5, col = i & 31;
    As[i] = Aatt[c * 128 + grp * 32 + col];
  }
  __syncthreads();
  const int r0 = tile * 512 + t * 2;               // rows r0, r0+1
  float acc0[32], acc1[32];
  {
    float x0 = X[r0], y0 = Y[r0], z0 = Z[r0];
    float x1 = X[r0 + 1], y1 = Y[r0 + 1], z1 = Z[r0 + 1];
    #pragma unroll
    for (int j = 0; j < 32; j += 4) {
      float4 a0 = *(const float4*)&As[0 * 32 + j];
      float4 a1 = *(const float4*)&As[1 * 32 + j];
      float4 a2 = *(const float4*)&As[2 * 32 + j];
      acc0[j]   = fmaf(z0, a2.x, fmaf(y0, a1.x, x0 * a0.x));
      acc0[j+1] = fmaf(z0, a2.y, fmaf(y0, a1.y, x0 * a0.y));
      acc0[j+2] = fmaf(z0, a2.z, fmaf(y0, a1.z, x0 * a0.z));
      acc0[j+3] = fmaf(z0, a2.w, fmaf(y0, a1.w, x0 * a0.w));
      acc1[j]   = fmaf(z1, a2.x, fmaf(y1, a1.x, x1 * a0.x));
      acc1[j+1] = fmaf(z1, a2.y, fmaf(y1, a1.y, x1 * a0.y));
      acc1[j+2] = fmaf(z1, a2.z, fmaf(y1, a1.z, x1 * a0.z));
      acc1[j+3] = fmaf(z1, a2.w, fmaf(y1, a1.w, x1 * a0.w));
    }
  }
  const float* m0 = mfeat + (size_t)r0 * 128;
  const float* m1 = m0 + 128;
  for (int c = 0; c < 128; c += 4) {
    float4 v0 = *(const float4*)(m0 + c);
    float4 v1 = *(const float4*)(m1 + c);
    #pragma unroll
    for (int u = 0; u < 4; u++) {
      const float* arow = &As[(3 + c + u) * 32];
      float s0 = u == 0 ? v0.x : u == 1 ? v0.y : u == 2 ? v0.z : v0.w;
      float s1 = u == 0 ? v1.x : u == 1 ? v1.y : u == 2 ? v1.z : v1.w;
      #pragma unroll
      for (int j = 0; j < 32; j += 4) {
        float4 a = *(const float4*)&arow[j];
        acc0[j]   = fmaf(s0, a.x, acc0[j]);
        acc0[j+1] = fmaf(s0, a.y, acc0[j+1]);
        acc0[j+2] = fmaf(s0, a.z, acc0[j+2]);
        acc0[j+3] = fmaf(s0, a.w, acc0[j+3]);
        acc1[j]   = fmaf(s1, a.x, acc1[j]);
        acc1[j+1] = fmaf(s1, a.y, acc1[j+1]);
        acc1[j+2] = fmaf(s1, a.z, acc1[j+2]);
        acc1[j+3] = fmaf(s1, a.w, acc1[j+3]);
      }
    }
  }
  float* p0 = P + (size_t)r0 * 128 + grp * 32;
  float* p1 = p0 + 128;
  #pragma unroll
  for (int j = 0; j < 32; j += 4) {
    *(float4*)(p0 + j) = make_float4(acc0[j], acc0[j+1], acc0[j+2], acc0[j+3]);
    *(float4*)(p1 + j) = make_float4(acc1[j], acc1[j+1], acc1[j+2], acc1[j+3]);
  }
}

__global__ __launch_bounds__(256) void f2_kernel(
    const float* __restrict__ X, const float* __restrict__ Y, const float* __restrict__ Z,
    const int* __restrict__ cidx, int* __restrict__ gidx,
    const float* __restrict__ mfeat, const float* __restrict__ Aatt,
    float* __restrict__ P) {
  __shared__ __align__(16) char smem[F2_SMEM];
  if (blockIdx.x < 2048)
    ballq_body(smem, X, Y, Z, cidx, gidx);
  else
    proj_body(smem, X, Y, Z, mfeat, Aatt, P);
}

// ---------------------------------------------------------------------------
// F3: attention-lite. logits = P[g] - P[c] (projection identity), leaky,
// softmax over n. Reductions: 4 VALU-DPP levels + 1 shfl-xor16 per value
// (48 DS ops/thread vs 240 with pure shfl). Division deferred past the
// reduction: out = sum(e*gf) / sum(e). Zero LDS; XCD-swizzled blocks.
// ---------------------------------------------------------------------------
__global__ __launch_bounds__(256) void attn_kernel(
    const float* __restrict__ X, const float* __restrict__ Y, const float* __restrict__ Z,
    const float* __restrict__ mfeat, const float* __restrict__ P,
    const int* __restrict__ cidx, const int* __restrict__ gidx,
    float* __restrict__ out) {
  const int pc = (blockIdx.x & 7) * 1024 + (blockIdx.x >> 3);  // batch-per-XCD
  const int b = pc >> 10;
  const int t = threadIdx.x;
  const int n = t & 31, q = t >> 5;                // q: 0..7, 16 channels each
  const int cI = cidx[pc];
  const int g = gidx[pc * NSAMPLE + n];
  const float* Pg = P + ((size_t)b * NPTS + g) * 128 + q * 16;
  const float* Pc = P + ((size_t)b * NPTS + cI) * 128 + q * 16;
  const float* Gf = mfeat + ((size_t)b * NPTS + g) * 128 + q * 16;
  float a[16], gfv[16];
  #pragma unroll
  for (int k = 0; k < 4; k++) {
    float4 vg = *(const float4*)(Pg + 4 * k);
    float4 vc = *(const float4*)(Pc + 4 * k);
    float4 vf = *(const float4*)(Gf + 4 * k);
    a[4*k]   = vg.x - vc.x; a[4*k+1] = vg.y - vc.y;
    a[4*k+2] = vg.z - vc.z; a[4*k+3] = vg.w - vc.w;
    gfv[4*k] = vf.x; gfv[4*k+1] = vf.y; gfv[4*k+2] = vf.z; gfv[4*k+3] = vf.w;
  }
  #pragma unroll
  for (int j = 0; j < 16; j++) a[j] = a[j] >= 0.0f ? a[j] : 0.2f * a[j];
  float e[16], s[16], num[16];
  #pragma unroll
  for (int j = 0; j < 16; j++) {
    float mx = red32_max(a[j]);
    e[j] = expf(a[j] - mx);
  }
  #pragma unroll
  for (int j = 0; j < 16; j++) s[j] = red32_sum(e[j]);
  #pragma unroll
  for (int j = 0; j < 16; j++) num[j] = red32_sum(e[j] * gfv[j]);
  if (n == 0) {
    float* orow = out + (size_t)pc * 131;
    #pragma unroll
    for (int j = 0; j < 16; j++) orow[3 + q * 16 + j] = num[j] / s[j];
    if (q == 0) {
      orow[0] = X[b * NPTS + cI]; orow[1] = Y[b * NPTS + cI]; orow[2] = Z[b * NPTS + cI];
    }
  }
}

// ---------------------------------------------------------------------------
extern "C" void kernel_launch(void* const* d_in, const int* in_sizes, int n_in,
                              void* d_out, int out_size, void* d_ws, size_t ws_size,
                              hipStream_t stream) {
  const float* points = (const float*)d_in[0];
  const float* W0 = (const float*)d_in[1];
  const float* B0 = (const float*)d_in[2];
  const float* G0 = (const float*)d_in[3];
  const float* E0 = (const float*)d_in[4];
  const float* W1 = (const float*)d_in[5];
  const float* B1 = (const float*)d_in[6];
  const float* G1 = (const float*)d_in[7];
  const float* E1 = (const float*)d_in[8];
  const float* W2 = (const float*)d_in[9];
  const float* B2 = (const float*)d_in[10];
  const float* G2 = (const float*)d_in[11];
  const float* E2 = (const float*)d_in[12];
  const float* Aatt = (const float*)d_in[13];
  float* out = (float*)d_out;

  // workspace (floats): mfeat 4.19M | P 4.19M | X/Y/Z 3*32k | cidx 8k | gidx 256k  (~35 MB)
  float* mfeat = (float*)d_ws;
  float* Pw = mfeat + (size_t)NBATCH * NPTS * 128;
  float* Xw = Pw + (size_t)NBATCH * NPTS * 128;
  float* Yw = Xw + NBATCH * NPTS;
  float* Zw = Yw + NBATCH * NPTS;
  int* cidxw = (int*)(Zw + NBATCH * NPTS);
  int* gidxw = cidxw + NBATCH * NPOINT;

  f1_kernel<<<8 + NBATCH * NPTS / 256, 256, 0, stream>>>(points,
      W0, B0, G0, E0, W1, B1, G1, E1, W2, B2, G2, E2, mfeat, cidxw, Xw, Yw, Zw);
  f2_kernel<<<2048 + 256, 256, 0, stream>>>(Xw, Yw, Zw, cidxw, gidxw, mfeat, Aatt, Pw);
  attn_kernel<<<NBATCH * NPOINT, 256, 0, stream>>>(Xw, Yw, Zw, mfeat, Pw, cidxw, gidxw, out);
}

// Round 8
// 864.649 us; speedup vs baseline: 1.2517x; 1.0378x over previous
//
#include <hip/hip_runtime.h>
#include <math.h>

#define NBATCH 8
#define NPTS 4096
#define NPOINT 1024
#define NSAMPLE 32
#define PTDIM 67        // 3 xyz + 64 feat
#define BIGF 1e10f

// DPP ctrl encodings (gfx9/CDNA)
#define DPP_QUAD_XOR1 0xB1   // quad_perm [1,0,3,2]
#define DPP_QUAD_XOR2 0x4E   // quad_perm [2,3,0,1]
#define DPP_ROW_HALF_MIRROR 0x141
#define DPP_ROW_MIRROR 0x140
#define DPP_ROW_BCAST15 0x142
#define DPP_ROW_BCAST31 0x143

// self-as-old DPP moves: un-sourced lanes keep self -> combine is a no-op there
template <int CTRL>
__device__ inline float dpp_mov_f(float v) {
  int i = __float_as_int(v);
  return __int_as_float(__builtin_amdgcn_update_dpp(i, i, CTRL, 0xf, 0xf, false));
}
template <int CTRL>
__device__ inline unsigned dpp_mov_u(unsigned v) {
  return (unsigned)__builtin_amdgcn_update_dpp((int)v, (int)v, CTRL, 0xf, 0xf, false);
}
// lexicographic u64 (hi,lo) min combine over a DPP pattern (VALU-only)
template <int CTRL>
__device__ inline void dpp_min2(unsigned& hi, unsigned& lo) {
  unsigned nh = dpp_mov_u<CTRL>(hi);
  unsigned nl = dpp_mov_u<CTRL>(lo);
  bool take = (nh < hi) || (nh == hi && nl < lo);
  hi = take ? nh : hi;
  lo = take ? nl : lo;
}
// monotone map f32 -> u32 (ascending order preserved, incl. negatives)
__device__ inline unsigned fmap(float d) {
  unsigned b = __float_as_uint(d);
  return ((int)b < 0) ? ~b : (b | 0x80000000u);
}
#define FMAP_INF 0xFF800000u   // fmap(+INF)

// 32-lane-group reductions: 4 VALU-DPP levels + ONE DS op (xor16) per value.
__device__ inline float red32_max(float v) {
  v = fmaxf(v, dpp_mov_f<DPP_QUAD_XOR1>(v));
  v = fmaxf(v, dpp_mov_f<DPP_QUAD_XOR2>(v));
  v = fmaxf(v, dpp_mov_f<DPP_ROW_HALF_MIRROR>(v));
  v = fmaxf(v, dpp_mov_f<DPP_ROW_MIRROR>(v));
  v = fmaxf(v, __shfl_xor(v, 16));
  return v;
}
__device__ inline float red32_sum(float v) {
  v += dpp_mov_f<DPP_QUAD_XOR1>(v);
  v += dpp_mov_f<DPP_QUAD_XOR2>(v);
  v += dpp_mov_f<DPP_ROW_HALF_MIRROR>(v);
  v += dpp_mov_f<DPP_ROW_MIRROR>(v);
  v += __shfl_xor(v, 16);
  return v;
}

// ---------------------------------------------------------------------------
// F1: fused FPS (blocks 0..7; also emits SoA xyz) + MLP (blocks 8..135).
// LDS overlaid via char buffer.
// ---------------------------------------------------------------------------
struct FpsS {
  unsigned long long slots[2][4];
  int cidxS[NPOINT];
  float4 C[NPTS];                                  // packed coords: 1 b128/lookup
};
struct MlpS {
  float w0[64 * 64], w1[64 * 64], w2[128 * 64];
  float bb0[64], ss0[64], ee0[64];
  float bb1[64], ss1[64], ee1[64];
  float bb2[128], ss2[128], ee2[128];
};
#define F1_SMEM (sizeof(MlpS) > sizeof(FpsS) ? sizeof(MlpS) : sizeof(FpsS))

// FPS: one block per batch, 256 thr, 16 pts/lane. R7 structure, but the
// distance+min update is written as float2 ops under `fp contract(off)`:
// lowers to v_pk_add_f32/v_pk_mul_f32 (dual-f32/instr, IEEE-identical per
// component, no FMA contraction) — halves the dist-loop issue (~144->~72
// instr). All selection/reduction logic byte-identical to R7.
// Exact f32 replication of jnp: ((dx*dx+dy*dy)+dz*dz), min, argmax first-idx.
__device__ void fps_body(char* smemRaw, const float* __restrict__ pts,
                         int* __restrict__ cidx, float* __restrict__ X,
                         float* __restrict__ Y, float* __restrict__ Z) {
#pragma clang fp contract(off)
  FpsS* S = (FpsS*)smemRaw;
  const int b = blockIdx.x, tid = threadIdx.x;
  const int w = tid >> 6, lane = tid & 63;
  const float* pb = pts + (size_t)b * NPTS * PTDIM;
  float2 px2[8], py2[8], pz2[8];
  float dl[16];
  #pragma unroll
  for (int k = 0; k < 16; k++) {
    int j = tid + (k << 8);
    const float* pj = pb + (size_t)j * PTDIM;
    float x = pj[0], y = pj[1], z = pj[2];
    if (k & 1) { px2[k >> 1].y = x; py2[k >> 1].y = y; pz2[k >> 1].y = z; }
    else       { px2[k >> 1].x = x; py2[k >> 1].x = y; pz2[k >> 1].x = z; }
    S->C[j] = make_float4(x, y, z, 0.0f);
    X[b * NPTS + j] = x; Y[b * NPTS + j] = y; Z[b * NPTS + j] = z;  // SoA out
    dl[k] = BIGF;
  }
  __syncthreads();
  int f = 0;
  float4 c0 = S->C[0];
  float cx = c0.x, cy = c0.y, cz = c0.z;
  for (int t = 0; t < NPOINT; t++) {
    if (tid == 0) S->cidxS[t] = f;                 // emit BEFORE update
    float2 c2x = make_float2(cx, cx);
    float2 c2y = make_float2(cy, cy);
    float2 c2z = make_float2(cz, cz);
    #pragma unroll
    for (int m = 0; m < 8; m++) {
      float2 dx = px2[m] - c2x;                    // v_pk_add_f32 (neg)
      float2 dy = py2[m] - c2y;
      float2 dz = pz2[m] - c2z;
      float2 d = (dx * dx + dy * dy) + dz * dz;    // pk_mul/pk_add, contract OFF
      dl[2 * m]     = fminf(dl[2 * m],     d.x);
      dl[2 * m + 1] = fminf(dl[2 * m + 1], d.y);
    }
    // per-lane max via tree (depth 4, independent ops)
    float u0 = fmaxf(dl[0], dl[1]),  u1 = fmaxf(dl[2], dl[3]);
    float u2 = fmaxf(dl[4], dl[5]),  u3 = fmaxf(dl[6], dl[7]);
    float u4 = fmaxf(dl[8], dl[9]),  u5 = fmaxf(dl[10], dl[11]);
    float u6 = fmaxf(dl[12], dl[13]), u7 = fmaxf(dl[14], dl[15]);
    float v0 = fmaxf(u0, u1), v1 = fmaxf(u2, u3);
    float v2 = fmaxf(u4, u5), v3 = fmaxf(u6, u7);
    float bv = fmaxf(fmaxf(v0, v1), fmaxf(v2, v3));
    // phase 1: wave max (2 instr/level, VALU-only)
    float m = bv;
    m = fmaxf(m, dpp_mov_f<DPP_QUAD_XOR1>(m));
    m = fmaxf(m, dpp_mov_f<DPP_QUAD_XOR2>(m));
    m = fmaxf(m, dpp_mov_f<DPP_ROW_HALF_MIRROR>(m));
    m = fmaxf(m, dpp_mov_f<DPP_ROW_MIRROR>(m));
    m = fmaxf(m, dpp_mov_f<DPP_ROW_BCAST15>(m));
    m = fmaxf(m, dpp_mov_f<DPP_ROW_BCAST31>(m));   // lane63 = wave max
    unsigned wmaxbits = (unsigned)__builtin_amdgcn_readlane(__float_as_int(m), 63);
    // phase 2: min index among (lane,k) holding the max — qualify + trees
    // (bit-equality exact: sums of squares never produce -0)
    unsigned c_[16];
    #pragma unroll
    for (int k = 0; k < 16; k++)
      c_[k] = (__float_as_uint(dl[k]) == wmaxbits) ? (unsigned)(tid + (k << 8)) : 0xFFFFFFFFu;
    unsigned q0 = min(c_[0], c_[1]),  q1 = min(c_[2], c_[3]);
    unsigned q2 = min(c_[4], c_[5]),  q3 = min(c_[6], c_[7]);
    unsigned q4 = min(c_[8], c_[9]),  q5 = min(c_[10], c_[11]);
    unsigned q6 = min(c_[12], c_[13]), q7 = min(c_[14], c_[15]);
    unsigned r0 = min(q0, q1), r1 = min(q2, q3), r2 = min(q4, q5), r3 = min(q6, q7);
    unsigned cand = min(min(r0, r1), min(r2, r3));
    cand = min(cand, dpp_mov_u<DPP_QUAD_XOR1>(cand));
    cand = min(cand, dpp_mov_u<DPP_QUAD_XOR2>(cand));
    cand = min(cand, dpp_mov_u<DPP_ROW_HALF_MIRROR>(cand));
    cand = min(cand, dpp_mov_u<DPP_ROW_MIRROR>(cand));
    cand = min(cand, dpp_mov_u<DPP_ROW_BCAST15>(cand));
    cand = min(cand, dpp_mov_u<DPP_ROW_BCAST31>(cand));  // lane63 = min j
    unsigned jmin = (unsigned)__builtin_amdgcn_readlane((int)cand, 63);
    if (lane == 0)
      S->slots[t & 1][w] = ((unsigned long long)wmaxbits << 32) |
                           (unsigned long long)(NPTS - 1 - jmin);  // bigger = smaller idx
    __syncthreads();
    unsigned long long s0 = S->slots[t & 1][0], s1 = S->slots[t & 1][1];
    unsigned long long s2 = S->slots[t & 1][2], s3 = S->slots[t & 1][3];
    unsigned long long m0 = s0 > s1 ? s0 : s1;
    unsigned long long m1 = s2 > s3 ? s2 : s3;
    unsigned long long best = m0 > m1 ? m0 : m1;
    f = NPTS - 1 - (int)(best & 0xFFFFFFFFull);
    float4 cc = S->C[f];                           // ONE b128 same-addr broadcast
    cx = cc.x; cy = cc.y; cz = cc.z;
  }
  __syncthreads();
  for (int i = tid; i < NPOINT; i += 256) cidx[b * NPOINT + i] = S->cidxS[i];
}

// MLP over ALL points (MLP∘gather == gather∘MLP). Thread-per-row, weights in
// LDS (broadcast reads), fully unrolled so x/h stay in VGPRs.
__device__ void mlp_body(char* smemRaw, const float* __restrict__ pts,
    const float* __restrict__ W0, const float* __restrict__ B0, const float* __restrict__ G0, const float* __restrict__ E0,
    const float* __restrict__ W1, const float* __restrict__ B1, const float* __restrict__ G1, const float* __restrict__ E1,
    const float* __restrict__ W2, const float* __restrict__ B2, const float* __restrict__ G2, const float* __restrict__ E2,
    float* __restrict__ mfeat) {
  MlpS* S = (MlpS*)smemRaw;
  const float INVS = 0.99999500003750f;            // 1/sqrt(1+1e-5)
  const int t = threadIdx.x;
  for (int i = t; i < 4096; i += 256) { S->w0[i] = W0[i]; S->w1[i] = W1[i]; }
  for (int i = t; i < 8192; i += 256) { S->w2[i] = W2[i]; }
  if (t < 64) {
    S->bb0[t] = B0[t]; S->ss0[t] = G0[t] * INVS; S->ee0[t] = E0[t];
    S->bb1[t] = B1[t]; S->ss1[t] = G1[t] * INVS; S->ee1[t] = E1[t];
  }
  if (t < 128) { S->bb2[t] = B2[t]; S->ss2[t] = G2[t] * INVS; S->ee2[t] = E2[t]; }
  __syncthreads();

  const size_t r = (size_t)(blockIdx.x - 8) * 256 + t;   // row 0..32767
  const float* xr = pts + r * PTDIM + 3;
  float x[64];
  #pragma unroll
  for (int c = 0; c < 64; c++) x[c] = xr[c];

  float h1[64];
  #pragma unroll
  for (int o = 0; o < 64; o++) {
    float acc = S->bb0[o];
    #pragma unroll
    for (int c = 0; c < 64; c += 4) {
      float4 wv = *(const float4*)&S->w0[o * 64 + c];
      acc = fmaf(wv.x, x[c], acc);
      acc = fmaf(wv.y, x[c + 1], acc);
      acc = fmaf(wv.z, x[c + 2], acc);
      acc = fmaf(wv.w, x[c + 3], acc);
    }
    h1[o] = fmaxf(fmaf(acc, S->ss0[o], S->ee0[o]), 0.0f);
  }
  float h2[64];
  #pragma unroll
  for (int o = 0; o < 64; o++) {
    float acc = S->bb1[o];
    #pragma unroll
    for (int c = 0; c < 64; c += 4) {
      float4 wv = *(const float4*)&S->w1[o * 64 + c];
      acc = fmaf(wv.x, h1[c], acc);
      acc = fmaf(wv.y, h1[c + 1], acc);
      acc = fmaf(wv.z, h1[c + 2], acc);
      acc = fmaf(wv.w, h1[c + 3], acc);
    }
    h2[o] = fmaxf(fmaf(acc, S->ss1[o], S->ee1[o]), 0.0f);
  }
  float* orow = mfeat + r * 128;
  #pragma unroll
  for (int o = 0; o < 128; o += 4) {
    float a0 = S->bb2[o], a1 = S->bb2[o + 1], a2 = S->bb2[o + 2], a3 = S->bb2[o + 3];
    #pragma unroll
    for (int c = 0; c < 64; c += 4) {
      float4 wv0 = *(const float4*)&S->w2[(o    ) * 64 + c];
      float4 wv1 = *(const float4*)&S->w2[(o + 1) * 64 + c];
      float4 wv2 = *(const float4*)&S->w2[(o + 2) * 64 + c];
      float4 wv3 = *(const float4*)&S->w2[(o + 3) * 64 + c];
      a0 = fmaf(wv0.x, h2[c], a0); a0 = fmaf(wv0.y, h2[c+1], a0); a0 = fmaf(wv0.z, h2[c+2], a0); a0 = fmaf(wv0.w, h2[c+3], a0);
      a1 = fmaf(wv1.x, h2[c], a1); a1 = fmaf(wv1.y, h2[c+1], a1); a1 = fmaf(wv1.z, h2[c+2], a1); a1 = fmaf(wv1.w, h2[c+3], a1);
      a2 = fmaf(wv2.x, h2[c], a2); a2 = fmaf(wv2.y, h2[c+1], a2); a2 = fmaf(wv2.z, h2[c+2], a2); a2 = fmaf(wv2.w, h2[c+3], a2);
      a3 = fmaf(wv3.x, h2[c], a3); a3 = fmaf(wv3.y, h2[c+1], a3); a3 = fmaf(wv3.z, h2[c+2], a3); a3 = fmaf(wv3.w, h2[c+3], a3);
    }
    float4 ov;
    ov.x = fmaxf(fmaf(a0, S->ss2[o    ], S->ee2[o    ]), 0.0f);
    ov.y = fmaxf(fmaf(a1, S->ss2[o + 1], S->ee2[o + 1]), 0.0f);
    ov.z = fmaxf(fmaf(a2, S->ss2[o + 2], S->ee2[o + 2]), 0.0f);
    ov.w = fmaxf(fmaf(a3, S->ss2[o + 3], S->ee2[o + 3]), 0.0f);
    *(float4*)(orow + o) = ov;
  }
}

__global__ __launch_bounds__(256) void f1_kernel(const float* __restrict__ pts,
    const float* __restrict__ W0, const float* __restrict__ B0, const float* __restrict__ G0, const float* __restrict__ E0,
    const float* __restrict__ W1, const float* __restrict__ B1, const float* __restrict__ G1, const float* __restrict__ E1,
    const float* __restrict__ W2, const float* __restrict__ B2, const float* __restrict__ G2, const float* __restrict__ E2,
    float* __restrict__ mfeat, int* __restrict__ cidx,
    float* __restrict__ X, float* __restrict__ Y, float* __restrict__ Z) {
  __shared__ __align__(16) char smem[F1_SMEM];
  if (blockIdx.x < 8)
    fps_body(smem, pts, cidx, X, Y, Z);
  else
    mlp_body(smem, pts, W0, B0, G0, E0, W1, B1, G1, E1, W2, B2, G2, E2, mfeat);
}

// ---------------------------------------------------------------------------
// F2: fused ball-query (blocks 0..2047) + attention projection P = [xyz,f]@A
// (blocks 2048..2303). LDS unioned (16.8 KB/block).
// ---------------------------------------------------------------------------
#define F2_SMEM 16768

// Ball query: one wave per center. Exact f32 replication of
// d = ((-2*dot)+sc)+sx, mask d>0.04f, stable-(d,idx) 32-smallest, pad w/first.
__device__ void ballq_body(char* smemRaw,
                           const float* __restrict__ X, const float* __restrict__ Y,
                           const float* __restrict__ Z, const int* __restrict__ cidx,
                           int* __restrict__ gidx) {
  float (*dbuf)[512] = (float (*)[512])smemRaw;
  int   (*ibuf)[512] = (int (*)[512])(smemRaw + 4 * 512 * 4);
  const int t = threadIdx.x;
  const int w = t >> 6, lane = t & 63;
  const int pc = blockIdx.x * 4 + w;               // 0..8191
  const int b = pc >> 10;
  const float* Xb = X + b * NPTS;
  const float* Yb = Y + b * NPTS;
  const float* Zb = Z + b * NPTS;
  const int cI = cidx[pc];
  const float cx = Xb[cI], cy = Yb[cI], cz = Zb[cI];
  const float sc = __fadd_rn(__fadd_rn(__fmul_rn(cx, cx), __fmul_rn(cy, cy)), __fmul_rn(cz, cz));
  const float R2 = 0.04f;
  int cnt = 0;                                     // wave-uniform
  for (int rr = 0; rr < 16; rr++) {
    const int base = rr * 256 + lane * 4;
    float4 px4 = *(const float4*)(Xb + base);
    float4 py4 = *(const float4*)(Yb + base);
    float4 pz4 = *(const float4*)(Zb + base);
    #pragma unroll
    for (int e = 0; e < 4; e++) {
      float px = e == 0 ? px4.x : e == 1 ? px4.y : e == 2 ? px4.z : px4.w;
      float py = e == 0 ? py4.x : e == 1 ? py4.y : e == 2 ? py4.z : py4.w;
      float pz = e == 0 ? pz4.x : e == 1 ? pz4.y : e == 2 ? pz4.z : pz4.w;
      float dot = __fadd_rn(__fadd_rn(__fmul_rn(cx, px), __fmul_rn(cy, py)), __fmul_rn(cz, pz));
      float sx  = __fadd_rn(__fadd_rn(__fmul_rn(px, px), __fmul_rn(py, py)), __fmul_rn(pz, pz));
      float d   = __fadd_rn(__fadd_rn(__fmul_rn(-2.0f, dot), sc), sx);
      bool pred = !(d > R2);
      unsigned long long mask = __ballot(pred);
      if (pred) {
        int pos = cnt + (int)__popcll(mask & ((1ull << lane) - 1ull));
        if (pos < 512) { dbuf[w][pos] = d; ibuf[w][pos] = base + e; }
      }
      cnt += (int)__popcll(mask);
    }
  }
  const int K = cnt < 512 ? cnt : 512;
  // u64 keys: hi = monotone-mapped d, lo = idx  ->  min key = (d,idx)-lex min
  unsigned long long kk[8];
  #pragma unroll
  for (int k = 0; k < 8; k++) {
    int pos = lane + 64 * k;
    if (pos < K)
      kk[k] = ((unsigned long long)fmap(dbuf[w][pos]) << 32) | (unsigned)ibuf[w][pos];
    else
      kk[k] = ((unsigned long long)FMAP_INF << 32) | 0x7fffffffu;
  }
  int first = 0;
  int* gout = gidx + pc * NSAMPLE;
  for (int it = 0; it < NSAMPLE; it++) {
    unsigned long long best = kk[0];
    #pragma unroll
    for (int k = 1; k < 8; k++) if (kk[k] < best) best = kk[k];
    unsigned hi = (unsigned)(best >> 32), lo = (unsigned)best;
    dpp_min2<DPP_QUAD_XOR1>(hi, lo);
    dpp_min2<DPP_QUAD_XOR2>(hi, lo);
    dpp_min2<DPP_ROW_HALF_MIRROR>(hi, lo);
    dpp_min2<DPP_ROW_MIRROR>(hi, lo);
    dpp_min2<DPP_ROW_BCAST15>(hi, lo);
    dpp_min2<DPP_ROW_BCAST31>(hi, lo);             // lane63 = wave min
    unsigned blo = (unsigned)__builtin_amdgcn_readlane((int)lo, 63);
    #pragma unroll
    for (int k = 0; k < 8; k++)
      if ((unsigned)kk[k] == blo)
        kk[k] = (kk[k] & 0xFFFFFFFFull) | ((unsigned long long)FMAP_INF << 32);
    if (it == 0) first = (int)blo;
    if (lane == 0) gout[it] = (it < K) ? (int)blo : first;
  }
}

// P projection: block = (row-tile of 512) x (col-group of 32).
__device__ void proj_body(char* smemRaw,
                          const float* __restrict__ X, const float* __restrict__ Y,
                          const float* __restrict__ Z, const float* __restrict__ mfeat,
                          const float* __restrict__ Aatt, float* __restrict__ P) {
  float* As = (float*)smemRaw;                     // [131*32]
  const int t = threadIdx.x;
  const int pb = blockIdx.x - 2048;                // 0..255
  const int grp = pb & 3;                          // col group: cols grp*32..+32
  const int tile = pb >> 2;                        // 0..63 -> rows tile*512..+512
  for (int i = t; i < 131 * 32; i += 256) {
    int c = i >> 5, col = i & 31;
    As[i] = Aatt[c * 128 + grp * 32 + col];
  }
  __syncthreads();
  const int r0 = tile * 512 + t * 2;               // rows r0, r0+1
  float acc0[32], acc1[32];
  {
    float x0 = X[r0], y0 = Y[r0], z0 = Z[r0];
    float x1 = X[r0 + 1], y1 = Y[r0 + 1], z1 = Z[r0 + 1];
    #pragma unroll
    for (int j = 0; j < 32; j += 4) {
      float4 a0 = *(const float4*)&As[0 * 32 + j];
      float4 a1 = *(const float4*)&As[1 * 32 + j];
      float4 a2 = *(const float4*)&As[2 * 32 + j];
      acc0[j]   = fmaf(z0, a2.x, fmaf(y0, a1.x, x0 * a0.x));
      acc0[j+1] = fmaf(z0, a2.y, fmaf(y0, a1.y, x0 * a0.y));
      acc0[j+2] = fmaf(z0, a2.z, fmaf(y0, a1.z, x0 * a0.z));
      acc0[j+3] = fmaf(z0, a2.w, fmaf(y0, a1.w, x0 * a0.w));
      acc1[j]   = fmaf(z1, a2.x, fmaf(y1, a1.x, x1 * a0.x));
      acc1[j+1] = fmaf(z1, a2.y, fmaf(y1, a1.y, x1 * a0.y));
      acc1[j+2] = fmaf(z1, a2.z, fmaf(y1, a1.z, x1 * a0.z));
      acc1[j+3] = fmaf(z1, a2.w, fmaf(y1, a1.w, x1 * a0.w));
    }
  }
  const float* m0 = mfeat + (size_t)r0 * 128;
  const float* m1 = m0 + 128;
  for (int c = 0; c < 128; c += 4) {
    float4 v0 = *(const float4*)(m0 + c);
    float4 v1 = *(const float4*)(m1 + c);
    #pragma unroll
    for (int u = 0; u < 4; u++) {
      const float* arow = &As[(3 + c + u) * 32];
      float s0 = u == 0 ? v0.x : u == 1 ? v0.y : u == 2 ? v0.z : v0.w;
      float s1 = u == 0 ? v1.x : u == 1 ? v1.y : u == 2 ? v1.z : v1.w;
      #pragma unroll
      for (int j = 0; j < 32; j += 4) {
        float4 a = *(const float4*)&arow[j];
        acc0[j]   = fmaf(s0, a.x, acc0[j]);
        acc0[j+1] = fmaf(s0, a.y, acc0[j+1]);
        acc0[j+2] = fmaf(s0, a.z, acc0[j+2]);
        acc0[j+3] = fmaf(s0, a.w, acc0[j+3]);
        acc1[j]   = fmaf(s1, a.x, acc1[j]);
        acc1[j+1] = fmaf(s1, a.y, acc1[j+1]);
        acc1[j+2] = fmaf(s1, a.z, acc1[j+2]);
        acc1[j+3] = fmaf(s1, a.w, acc1[j+3]);
      }
    }
  }
  float* p0 = P + (size_t)r0 * 128 + grp * 32;
  float* p1 = p0 + 128;
  #pragma unroll
  for (int j = 0; j < 32; j += 4) {
    *(float4*)(p0 + j) = make_float4(acc0[j], acc0[j+1], acc0[j+2], acc0[j+3]);
    *(float4*)(p1 + j) = make_float4(acc1[j], acc1[j+1], acc1[j+2], acc1[j+3]);
  }
}

__global__ __launch_bounds__(256) void f2_kernel(
    const float* __restrict__ X, const float* __restrict__ Y, const float* __restrict__ Z,
    const int* __restrict__ cidx, int* __restrict__ gidx,
    const float* __restrict__ mfeat, const float* __restrict__ Aatt,
    float* __restrict__ P) {
  __shared__ __align__(16) char smem[F2_SMEM];
  if (blockIdx.x < 2048)
    ballq_body(smem, X, Y, Z, cidx, gidx);
  else
    proj_body(smem, X, Y, Z, mfeat, Aatt, P);
}

// ---------------------------------------------------------------------------
// F3: attention-lite. logits = P[g] - P[c] (projection identity), leaky,
// softmax over n. Center row Pc staged in LDS once per block (was 32x
// redundant 64B gathers). Reductions: 4 VALU-DPP levels + 1 shfl-xor16.
// out = sum(e*gf) / sum(e). XCD-swizzled blocks.
// ---------------------------------------------------------------------------
__global__ __launch_bounds__(256) void attn_kernel(
    const float* __restrict__ X, const float* __restrict__ Y, const float* __restrict__ Z,
    const float* __restrict__ mfeat, const float* __restrict__ P,
    const int* __restrict__ cidx, const int* __restrict__ gidx,
    float* __restrict__ out) {
  __shared__ float pcS[128];
  const int pc = (blockIdx.x & 7) * 1024 + (blockIdx.x >> 3);  // batch-per-XCD
  const int b = pc >> 10;
  const int t = threadIdx.x;
  const int n = t & 31, q = t >> 5;                // q: 0..7, 16 channels each
  const int cI = cidx[pc];
  if (t < 128) pcS[t] = P[((size_t)b * NPTS + cI) * 128 + t];
  const int g = gidx[pc * NSAMPLE + n];
  const float* Pg = P + ((size_t)b * NPTS + g) * 128 + q * 16;
  const float* Gf = mfeat + ((size_t)b * NPTS + g) * 128 + q * 16;
  __syncthreads();
  float a[16], gfv[16];
  #pragma unroll
  for (int k = 0; k < 4; k++) {
    float4 vg = *(const float4*)(Pg + 4 * k);
    float4 vc = *(const float4*)&pcS[q * 16 + 4 * k];   // LDS broadcast
    float4 vf = *(const float4*)(Gf + 4 * k);
    a[4*k]   = vg.x - vc.x; a[4*k+1] = vg.y - vc.y;
    a[4*k+2] = vg.z - vc.z; a[4*k+3] = vg.w - vc.w;
    gfv[4*k] = vf.x; gfv[4*k+1] = vf.y; gfv[4*k+2] = vf.z; gfv[4*k+3] = vf.w;
  }
  #pragma unroll
  for (int j = 0; j < 16; j++) a[j] = a[j] >= 0.0f ? a[j] : 0.2f * a[j];
  float e[16], s[16], num[16];
  #pragma unroll
  for (int j = 0; j < 16; j++) {
    float mx = red32_max(a[j]);
    e[j] = expf(a[j] - mx);
  }
  #pragma unroll
  for (int j = 0; j < 16; j++) s[j] = red32_sum(e[j]);
  #pragma unroll
  for (int j = 0; j < 16; j++) num[j] = red32_sum(e[j] * gfv[j]);
  if (n == 0) {
    float* orow = out + (size_t)pc * 131;
    #pragma unroll
    for (int j = 0; j < 16; j++) orow[3 + q * 16 + j] = num[j] / s[j];
    if (q == 0) {
      orow[0] = X[b * NPTS + cI]; orow[1] = Y[b * NPTS + cI]; orow[2] = Z[b * NPTS + cI];
    }
  }
}

// ---------------------------------------------------------------------------
extern "C" void kernel_launch(void* const* d_in, const int* in_sizes, int n_in,
                              void* d_out, int out_size, void* d_ws, size_t ws_size,
                              hipStream_t stream) {
  const float* points = (const float*)d_in[0];
  const float* W0 = (const float*)d_in[1];
  const float* B0 = (const float*)d_in[2];
  const float* G0 = (const float*)d_in[3];
  const float* E0 = (const float*)d_in[4];
  const float* W1 = (const float*)d_in[5];
  const float* B1 = (const float*)d_in[6];
  const float* G1 = (const float*)d_in[7];
  const float* E1 = (const float*)d_in[8];
  const float* W2 = (const float*)d_in[9];
  const float* B2 = (const float*)d_in[10];
  const float* G2 = (const float*)d_in[11];
  const float* E2 = (const float*)d_in[12];
  const float* Aatt = (const float*)d_in[13];
  float* out = (float*)d_out;

  // workspace (floats): mfeat 4.19M | P 4.19M | X/Y/Z 3*32k | cidx 8k | gidx 256k  (~35 MB)
  float* mfeat = (float*)d_ws;
  float* Pw = mfeat + (size_t)NBATCH * NPTS * 128;
  float* Xw = Pw + (size_t)NBATCH * NPTS * 128;
  float* Yw = Xw + NBATCH * NPTS;
  float* Zw = Yw + NBATCH * NPTS;
  int* cidxw = (int*)(Zw + NBATCH * NPTS);
  int* gidxw = cidxw + NBATCH * NPOINT;

  f1_kernel<<<8 + NBATCH * NPTS / 256, 256, 0, stream>>>(points,
      W0, B0, G0, E0, W1, B1, G1, E1, W2, B2, G2, E2, mfeat, cidxw, Xw, Yw, Zw);
  f2_kernel<<<2048 + 256, 256, 0, stream>>>(Xw, Yw, Zw, cidxw, gidxw, mfeat, Aatt, Pw);
  attn_kernel<<<NBATCH * NPOINT, 256, 0, stream>>>(Xw, Yw, Zw, mfeat, Pw, cidxw, gidxw, out);
}

// Round 9
// 833.538 us; speedup vs baseline: 1.2984x; 1.0373x over previous
//
#include <hip/hip_runtime.h>
#include <math.h>

#define NBATCH 8
#define NPTS 4096
#define NPOINT 1024
#define NSAMPLE 32
#define PTDIM 67        // 3 xyz + 64 feat
#define BIGF 1e10f

// DPP ctrl encodings (gfx9/CDNA)
#define DPP_QUAD_XOR1 0xB1   // quad_perm [1,0,3,2]
#define DPP_QUAD_XOR2 0x4E   // quad_perm [2,3,0,1]
#define DPP_ROW_HALF_MIRROR 0x141
#define DPP_ROW_MIRROR 0x140
#define DPP_ROW_BCAST15 0x142
#define DPP_ROW_BCAST31 0x143

template <int CTRL>
__device__ inline float dpp_mov_f(float v) {
  int i = __float_as_int(v);
  return __int_as_float(__builtin_amdgcn_update_dpp(i, i, CTRL, 0xf, 0xf, false));
}
template <int CTRL>
__device__ inline unsigned dpp_mov_u(unsigned v) {
  return (unsigned)__builtin_amdgcn_update_dpp((int)v, (int)v, CTRL, 0xf, 0xf, false);
}
template <int CTRL>
__device__ inline void dpp_min2(unsigned& hi, unsigned& lo) {
  unsigned nh = dpp_mov_u<CTRL>(hi);
  unsigned nl = dpp_mov_u<CTRL>(lo);
  bool take = (nh < hi) || (nh == hi && nl < lo);
  hi = take ? nh : hi;
  lo = take ? nl : lo;
}
__device__ inline unsigned fmap(float d) {
  unsigned b = __float_as_uint(d);
  return ((int)b < 0) ? ~b : (b | 0x80000000u);
}
#define FMAP_INF 0xFF800000u   // fmap(+INF)

// 32-lane-group reductions: 4 VALU-DPP levels + ONE DS op (xor16) per value.
__device__ inline float red32_max(float v) {
  v = fmaxf(v, dpp_mov_f<DPP_QUAD_XOR1>(v));
  v = fmaxf(v, dpp_mov_f<DPP_QUAD_XOR2>(v));
  v = fmaxf(v, dpp_mov_f<DPP_ROW_HALF_MIRROR>(v));
  v = fmaxf(v, dpp_mov_f<DPP_ROW_MIRROR>(v));
  v = fmaxf(v, __shfl_xor(v, 16));
  return v;
}
__device__ inline float red32_sum(float v) {
  v += dpp_mov_f<DPP_QUAD_XOR1>(v);
  v += dpp_mov_f<DPP_QUAD_XOR2>(v);
  v += dpp_mov_f<DPP_ROW_HALF_MIRROR>(v);
  v += dpp_mov_f<DPP_ROW_MIRROR>(v);
  v += __shfl_xor(v, 16);
  return v;
}

// ---------------------------------------------------------------------------
// F1: fused FPS (blocks 0..7; also emits SoA xyz) + PROJ-MLP (blocks 8..71).
// projmlp recomputes the MLP per row in-register (bit-identical op order ->
// h3 == mfeat row) and writes BOTH mfeat and P = [xyz,h3]@A. This removes the
// mfeat cross-block dependency, so ALL matmul work runs concurrently with FPS
// on the 248 spare CUs instead of serializing after f1.
// ---------------------------------------------------------------------------
struct FpsS {
  unsigned long long slots[2][4];
  int cidxS[NPOINT];
  float4 C[NPTS];
};
struct ProjS {
  float As[131 * 128];                             // a_att row-major
  float w0[64 * 64], w1[64 * 64], w2[128 * 64];
  float bb0[64], ss0[64], ee0[64];
  float bb1[64], ss1[64], ee1[64];
  float bb2[128], ss2[128], ee2[128];
};
#define F1_SMEM (sizeof(ProjS) > sizeof(FpsS) ? sizeof(ProjS) : sizeof(FpsS))

// FPS: one block per batch, 256 thr, 16 pts/lane, pk-f32 dist update under
// contract(off) (IEEE-identical per component). Split-phase DPP argmax.
// Exact f32 replication of jnp: ((dx*dx+dy*dy)+dz*dz), min, argmax first-idx.
__device__ void fps_body(char* smemRaw, const float* __restrict__ pts,
                         int* __restrict__ cidx, float* __restrict__ X,
                         float* __restrict__ Y, float* __restrict__ Z) {
#pragma clang fp contract(off)
  FpsS* S = (FpsS*)smemRaw;
  const int b = blockIdx.x, tid = threadIdx.x;
  const int w = tid >> 6, lane = tid & 63;
  const float* pb = pts + (size_t)b * NPTS * PTDIM;
  float2 px2[8], py2[8], pz2[8];
  float dl[16];
  #pragma unroll
  for (int k = 0; k < 16; k++) {
    int j = tid + (k << 8);
    const float* pj = pb + (size_t)j * PTDIM;
    float x = pj[0], y = pj[1], z = pj[2];
    if (k & 1) { px2[k >> 1].y = x; py2[k >> 1].y = y; pz2[k >> 1].y = z; }
    else       { px2[k >> 1].x = x; py2[k >> 1].x = y; pz2[k >> 1].x = z; }
    S->C[j] = make_float4(x, y, z, 0.0f);
    X[b * NPTS + j] = x; Y[b * NPTS + j] = y; Z[b * NPTS + j] = z;  // SoA out
    dl[k] = BIGF;
  }
  __syncthreads();
  int f = 0;
  float4 c0 = S->C[0];
  float cx = c0.x, cy = c0.y, cz = c0.z;
  for (int t = 0; t < NPOINT; t++) {
    if (tid == 0) S->cidxS[t] = f;                 // emit BEFORE update
    float2 c2x = make_float2(cx, cx);
    float2 c2y = make_float2(cy, cy);
    float2 c2z = make_float2(cz, cz);
    #pragma unroll
    for (int m = 0; m < 8; m++) {
      float2 dx = px2[m] - c2x;
      float2 dy = py2[m] - c2y;
      float2 dz = pz2[m] - c2z;
      float2 d = (dx * dx + dy * dy) + dz * dz;    // pk ops, contract OFF
      dl[2 * m]     = fminf(dl[2 * m],     d.x);
      dl[2 * m + 1] = fminf(dl[2 * m + 1], d.y);
    }
    float u0 = fmaxf(dl[0], dl[1]),  u1 = fmaxf(dl[2], dl[3]);
    float u2 = fmaxf(dl[4], dl[5]),  u3 = fmaxf(dl[6], dl[7]);
    float u4 = fmaxf(dl[8], dl[9]),  u5 = fmaxf(dl[10], dl[11]);
    float u6 = fmaxf(dl[12], dl[13]), u7 = fmaxf(dl[14], dl[15]);
    float v0 = fmaxf(u0, u1), v1 = fmaxf(u2, u3);
    float v2 = fmaxf(u4, u5), v3 = fmaxf(u6, u7);
    float bv = fmaxf(fmaxf(v0, v1), fmaxf(v2, v3));
    float m = bv;
    m = fmaxf(m, dpp_mov_f<DPP_QUAD_XOR1>(m));
    m = fmaxf(m, dpp_mov_f<DPP_QUAD_XOR2>(m));
    m = fmaxf(m, dpp_mov_f<DPP_ROW_HALF_MIRROR>(m));
    m = fmaxf(m, dpp_mov_f<DPP_ROW_MIRROR>(m));
    m = fmaxf(m, dpp_mov_f<DPP_ROW_BCAST15>(m));
    m = fmaxf(m, dpp_mov_f<DPP_ROW_BCAST31>(m));   // lane63 = wave max
    unsigned wmaxbits = (unsigned)__builtin_amdgcn_readlane(__float_as_int(m), 63);
    // min index among holders (bit-equality exact: no -0 from sums of squares)
    unsigned c_[16];
    #pragma unroll
    for (int k = 0; k < 16; k++)
      c_[k] = (__float_as_uint(dl[k]) == wmaxbits) ? (unsigned)(tid + (k << 8)) : 0xFFFFFFFFu;
    unsigned q0 = min(c_[0], c_[1]),  q1 = min(c_[2], c_[3]);
    unsigned q2 = min(c_[4], c_[5]),  q3 = min(c_[6], c_[7]);
    unsigned q4 = min(c_[8], c_[9]),  q5 = min(c_[10], c_[11]);
    unsigned q6 = min(c_[12], c_[13]), q7 = min(c_[14], c_[15]);
    unsigned r0 = min(q0, q1), r1 = min(q2, q3), r2 = min(q4, q5), r3 = min(q6, q7);
    unsigned cand = min(min(r0, r1), min(r2, r3));
    cand = min(cand, dpp_mov_u<DPP_QUAD_XOR1>(cand));
    cand = min(cand, dpp_mov_u<DPP_QUAD_XOR2>(cand));
    cand = min(cand, dpp_mov_u<DPP_ROW_HALF_MIRROR>(cand));
    cand = min(cand, dpp_mov_u<DPP_ROW_MIRROR>(cand));
    cand = min(cand, dpp_mov_u<DPP_ROW_BCAST15>(cand));
    cand = min(cand, dpp_mov_u<DPP_ROW_BCAST31>(cand));  // lane63 = min j
    unsigned jmin = (unsigned)__builtin_amdgcn_readlane((int)cand, 63);
    if (lane == 0)
      S->slots[t & 1][w] = ((unsigned long long)wmaxbits << 32) |
                           (unsigned long long)(NPTS - 1 - jmin);
    __syncthreads();
    unsigned long long s0 = S->slots[t & 1][0], s1 = S->slots[t & 1][1];
    unsigned long long s2 = S->slots[t & 1][2], s3 = S->slots[t & 1][3];
    unsigned long long m0 = s0 > s1 ? s0 : s1;
    unsigned long long m1 = s2 > s3 ? s2 : s3;
    unsigned long long best = m0 > m1 ? m0 : m1;
    f = NPTS - 1 - (int)(best & 0xFFFFFFFFull);
    float4 cc = S->C[f];
    cx = cc.x; cy = cc.y; cz = cc.z;
  }
  __syncthreads();
  for (int i = tid; i < NPOINT; i += 256) cidx[b * NPOINT + i] = S->cidxS[i];
}

// PROJ-MLP: 64 blocks x 512 rows (2 rows/thread, sequential). Per row:
// MLP (op-order identical to the old mlp_body -> h3 bits == mfeat bits),
// write mfeat, then P = [xyz,h3]@A with ascending-c accumulation (identical
// to the old proj_body order). A + weights staged in LDS (~135.7 KB).
__device__ void projmlp_body(char* smemRaw, const float* __restrict__ pts,
    const float* __restrict__ W0, const float* __restrict__ B0, const float* __restrict__ G0, const float* __restrict__ E0,
    const float* __restrict__ W1, const float* __restrict__ B1, const float* __restrict__ G1, const float* __restrict__ E1,
    const float* __restrict__ W2, const float* __restrict__ B2, const float* __restrict__ G2, const float* __restrict__ E2,
    const float* __restrict__ Aatt,
    float* __restrict__ mfeat, float* __restrict__ P) {
  ProjS* S = (ProjS*)smemRaw;
  const float INVS = 0.99999500003750f;            // 1/sqrt(1+1e-5)
  const int t = threadIdx.x;
  for (int i = t; i < 131 * 128; i += 256) S->As[i] = Aatt[i];
  for (int i = t; i < 4096; i += 256) { S->w0[i] = W0[i]; S->w1[i] = W1[i]; }
  for (int i = t; i < 8192; i += 256) S->w2[i] = W2[i];
  if (t < 64) {
    S->bb0[t] = B0[t]; S->ss0[t] = G0[t] * INVS; S->ee0[t] = E0[t];
    S->bb1[t] = B1[t]; S->ss1[t] = G1[t] * INVS; S->ee1[t] = E1[t];
  }
  if (t < 128) { S->bb2[t] = B2[t]; S->ss2[t] = G2[t] * INVS; S->ee2[t] = E2[t]; }
  __syncthreads();

  const int pb = blockIdx.x - 8;                   // 0..63
  for (int rr = 0; rr < 2; rr++) {
    const size_t r = (size_t)pb * 512 + rr * 256 + t;   // row 0..32767
    const float* xr = pts + r * PTDIM + 3;
    float x[64];
    #pragma unroll
    for (int c = 0; c < 64; c++) x[c] = xr[c];

    float h1[64];
    #pragma unroll
    for (int o = 0; o < 64; o++) {
      float acc = S->bb0[o];
      #pragma unroll
      for (int c = 0; c < 64; c += 4) {
        float4 wv = *(const float4*)&S->w0[o * 64 + c];
        acc = fmaf(wv.x, x[c], acc);
        acc = fmaf(wv.y, x[c + 1], acc);
        acc = fmaf(wv.z, x[c + 2], acc);
        acc = fmaf(wv.w, x[c + 3], acc);
      }
      h1[o] = fmaxf(fmaf(acc, S->ss0[o], S->ee0[o]), 0.0f);
    }
    float h2[64];
    #pragma unroll
    for (int o = 0; o < 64; o++) {
      float acc = S->bb1[o];
      #pragma unroll
      for (int c = 0; c < 64; c += 4) {
        float4 wv = *(const float4*)&S->w1[o * 64 + c];
        acc = fmaf(wv.x, h1[c], acc);
        acc = fmaf(wv.y, h1[c + 1], acc);
        acc = fmaf(wv.z, h1[c + 2], acc);
        acc = fmaf(wv.w, h1[c + 3], acc);
      }
      h2[o] = fmaxf(fmaf(acc, S->ss1[o], S->ee1[o]), 0.0f);
    }
    float h3[128];
    float* orow = mfeat + r * 128;
    #pragma unroll
    for (int o = 0; o < 128; o += 4) {
      float a0 = S->bb2[o], a1 = S->bb2[o + 1], a2 = S->bb2[o + 2], a3 = S->bb2[o + 3];
      #pragma unroll
      for (int c = 0; c < 64; c += 4) {
        float4 wv0 = *(const float4*)&S->w2[(o    ) * 64 + c];
        float4 wv1 = *(const float4*)&S->w2[(o + 1) * 64 + c];
        float4 wv2 = *(const float4*)&S->w2[(o + 2) * 64 + c];
        float4 wv3 = *(const float4*)&S->w2[(o + 3) * 64 + c];
        a0 = fmaf(wv0.x, h2[c], a0); a0 = fmaf(wv0.y, h2[c+1], a0); a0 = fmaf(wv0.z, h2[c+2], a0); a0 = fmaf(wv0.w, h2[c+3], a0);
        a1 = fmaf(wv1.x, h2[c], a1); a1 = fmaf(wv1.y, h2[c+1], a1); a1 = fmaf(wv1.z, h2[c+2], a1); a1 = fmaf(wv1.w, h2[c+3], a1);
        a2 = fmaf(wv2.x, h2[c], a2); a2 = fmaf(wv2.y, h2[c+1], a2); a2 = fmaf(wv2.z, h2[c+2], a2); a2 = fmaf(wv2.w, h2[c+3], a2);
        a3 = fmaf(wv3.x, h2[c], a3); a3 = fmaf(wv3.y, h2[c+1], a3); a3 = fmaf(wv3.z, h2[c+2], a3); a3 = fmaf(wv3.w, h2[c+3], a3);
      }
      float4 ov;
      ov.x = fmaxf(fmaf(a0, S->ss2[o    ], S->ee2[o    ]), 0.0f);
      ov.y = fmaxf(fmaf(a1, S->ss2[o + 1], S->ee2[o + 1]), 0.0f);
      ov.z = fmaxf(fmaf(a2, S->ss2[o + 2], S->ee2[o + 2]), 0.0f);
      ov.w = fmaxf(fmaf(a3, S->ss2[o + 3], S->ee2[o + 3]), 0.0f);
      h3[o] = ov.x; h3[o + 1] = ov.y; h3[o + 2] = ov.z; h3[o + 3] = ov.w;
      *(float4*)(orow + o) = ov;
    }
    // P row = [xyz, h3] @ A   (ascending-c order, matches old proj_body)
    const float* pr = pts + r * PTDIM;
    float x0 = pr[0], y0 = pr[1], z0 = pr[2];
    float* prow = P + r * 128;
    for (int grp = 0; grp < 4; grp++) {
      const int g0 = grp * 32;
      float acc[32];
      #pragma unroll
      for (int j = 0; j < 32; j++) {
        float a0 = S->As[0 * 128 + g0 + j];
        float a1 = S->As[1 * 128 + g0 + j];
        float a2 = S->As[2 * 128 + g0 + j];
        acc[j] = fmaf(z0, a2, fmaf(y0, a1, x0 * a0));
      }
      #pragma unroll
      for (int c = 0; c < 128; c++) {
        float s = h3[c];
        const float* arow = &S->As[(3 + c) * 128 + g0];
        #pragma unroll
        for (int j = 0; j < 32; j += 4) {
          float4 a = *(const float4*)&arow[j];
          acc[j]   = fmaf(s, a.x, acc[j]);
          acc[j+1] = fmaf(s, a.y, acc[j+1]);
          acc[j+2] = fmaf(s, a.z, acc[j+2]);
          acc[j+3] = fmaf(s, a.w, acc[j+3]);
        }
      }
      #pragma unroll
      for (int j = 0; j < 32; j += 4)
        *(float4*)(prow + g0 + j) = make_float4(acc[j], acc[j+1], acc[j+2], acc[j+3]);
    }
  }
}

__global__ __launch_bounds__(256) void f1_kernel(const float* __restrict__ pts,
    const float* __restrict__ W0, const float* __restrict__ B0, const float* __restrict__ G0, const float* __restrict__ E0,
    const float* __restrict__ W1, const float* __restrict__ B1, const float* __restrict__ G1, const float* __restrict__ E1,
    const float* __restrict__ W2, const float* __restrict__ B2, const float* __restrict__ G2, const float* __restrict__ E2,
    const float* __restrict__ Aatt,
    float* __restrict__ mfeat, float* __restrict__ P, int* __restrict__ cidx,
    float* __restrict__ X, float* __restrict__ Y, float* __restrict__ Z) {
  __shared__ __align__(16) char smem[F1_SMEM];
  if (blockIdx.x < 8)
    fps_body(smem, pts, cidx, X, Y, Z);
  else
    projmlp_body(smem, pts, W0, B0, G0, E0, W1, B1, G1, E1, W2, B2, G2, E2,
                 Aatt, mfeat, P);
}

// ---------------------------------------------------------------------------
// F2: ball query only (2048 blocks, 1 wave/center). Exact f32 replication of
// d = ((-2*dot)+sc)+sx, mask d>0.04f, stable-(d,idx) 32-smallest, pad w/first.
// ---------------------------------------------------------------------------
__global__ __launch_bounds__(256) void f2_kernel(
    const float* __restrict__ X, const float* __restrict__ Y, const float* __restrict__ Z,
    const int* __restrict__ cidx, int* __restrict__ gidx) {
  __shared__ float dbuf[4][512];
  __shared__ int   ibuf[4][512];
  const int t = threadIdx.x;
  const int w = t >> 6, lane = t & 63;
  const int pc = blockIdx.x * 4 + w;               // 0..8191
  const int b = pc >> 10;
  const float* Xb = X + b * NPTS;
  const float* Yb = Y + b * NPTS;
  const float* Zb = Z + b * NPTS;
  const int cI = cidx[pc];
  const float cx = Xb[cI], cy = Yb[cI], cz = Zb[cI];
  const float sc = __fadd_rn(__fadd_rn(__fmul_rn(cx, cx), __fmul_rn(cy, cy)), __fmul_rn(cz, cz));
  const float R2 = 0.04f;
  int cnt = 0;                                     // wave-uniform
  for (int rr = 0; rr < 16; rr++) {
    const int base = rr * 256 + lane * 4;
    float4 px4 = *(const float4*)(Xb + base);
    float4 py4 = *(const float4*)(Yb + base);
    float4 pz4 = *(const float4*)(Zb + base);
    #pragma unroll
    for (int e = 0; e < 4; e++) {
      float px = e == 0 ? px4.x : e == 1 ? px4.y : e == 2 ? px4.z : px4.w;
      float py = e == 0 ? py4.x : e == 1 ? py4.y : e == 2 ? py4.z : py4.w;
      float pz = e == 0 ? pz4.x : e == 1 ? pz4.y : e == 2 ? pz4.z : pz4.w;
      float dot = __fadd_rn(__fadd_rn(__fmul_rn(cx, px), __fmul_rn(cy, py)), __fmul_rn(cz, pz));
      float sx  = __fadd_rn(__fadd_rn(__fmul_rn(px, px), __fmul_rn(py, py)), __fmul_rn(pz, pz));
      float d   = __fadd_rn(__fadd_rn(__fmul_rn(-2.0f, dot), sc), sx);
      bool pred = !(d > R2);
      unsigned long long mask = __ballot(pred);
      if (pred) {
        int pos = cnt + (int)__popcll(mask & ((1ull << lane) - 1ull));
        if (pos < 512) { dbuf[w][pos] = d; ibuf[w][pos] = base + e; }
      }
      cnt += (int)__popcll(mask);
    }
  }
  const int K = cnt < 512 ? cnt : 512;
  unsigned long long kk[8];
  #pragma unroll
  for (int k = 0; k < 8; k++) {
    int pos = lane + 64 * k;
    if (pos < K)
      kk[k] = ((unsigned long long)fmap(dbuf[w][pos]) << 32) | (unsigned)ibuf[w][pos];
    else
      kk[k] = ((unsigned long long)FMAP_INF << 32) | 0x7fffffffu;
  }
  int first = 0;
  int* gout = gidx + pc * NSAMPLE;
  for (int it = 0; it < NSAMPLE; it++) {
    unsigned long long best = kk[0];
    #pragma unroll
    for (int k = 1; k < 8; k++) if (kk[k] < best) best = kk[k];
    unsigned hi = (unsigned)(best >> 32), lo = (unsigned)best;
    dpp_min2<DPP_QUAD_XOR1>(hi, lo);
    dpp_min2<DPP_QUAD_XOR2>(hi, lo);
    dpp_min2<DPP_ROW_HALF_MIRROR>(hi, lo);
    dpp_min2<DPP_ROW_MIRROR>(hi, lo);
    dpp_min2<DPP_ROW_BCAST15>(hi, lo);
    dpp_min2<DPP_ROW_BCAST31>(hi, lo);             // lane63 = wave min
    unsigned blo = (unsigned)__builtin_amdgcn_readlane((int)lo, 63);
    #pragma unroll
    for (int k = 0; k < 8; k++)
      if ((unsigned)kk[k] == blo)
        kk[k] = (kk[k] & 0xFFFFFFFFull) | ((unsigned long long)FMAP_INF << 32);
    if (it == 0) first = (int)blo;
    if (lane == 0) gout[it] = (it < K) ? (int)blo : first;
  }
}

// ---------------------------------------------------------------------------
// F3: attention-lite. logits = P[g] - P[c], leaky, softmax over n.
// Pc staged in LDS once per block. Reductions: 4 VALU-DPP + 1 shfl-xor16.
// out = sum(e*gf) / sum(e). XCD-swizzled blocks.
// ---------------------------------------------------------------------------
__global__ __launch_bounds__(256) void attn_kernel(
    const float* __restrict__ X, const float* __restrict__ Y, const float* __restrict__ Z,
    const float* __restrict__ mfeat, const float* __restrict__ P,
    const int* __restrict__ cidx, const int* __restrict__ gidx,
    float* __restrict__ out) {
  __shared__ float pcS[128];
  const int pc = (blockIdx.x & 7) * 1024 + (blockIdx.x >> 3);  // batch-per-XCD
  const int b = pc >> 10;
  const int t = threadIdx.x;
  const int n = t & 31, q = t >> 5;                // q: 0..7, 16 channels each
  const int cI = cidx[pc];
  if (t < 128) pcS[t] = P[((size_t)b * NPTS + cI) * 128 + t];
  const int g = gidx[pc * NSAMPLE + n];
  const float* Pg = P + ((size_t)b * NPTS + g) * 128 + q * 16;
  const float* Gf = mfeat + ((size_t)b * NPTS + g) * 128 + q * 16;
  __syncthreads();
  float a[16], gfv[16];
  #pragma unroll
  for (int k = 0; k < 4; k++) {
    float4 vg = *(const float4*)(Pg + 4 * k);
    float4 vc = *(const float4*)&pcS[q * 16 + 4 * k];   // LDS broadcast
    float4 vf = *(const float4*)(Gf + 4 * k);
    a[4*k]   = vg.x - vc.x; a[4*k+1] = vg.y - vc.y;
    a[4*k+2] = vg.z - vc.z; a[4*k+3] = vg.w - vc.w;
    gfv[4*k] = vf.x; gfv[4*k+1] = vf.y; gfv[4*k+2] = vf.z; gfv[4*k+3] = vf.w;
  }
  #pragma unroll
  for (int j = 0; j < 16; j++) a[j] = a[j] >= 0.0f ? a[j] : 0.2f * a[j];
  float e[16], s[16], num[16];
  #pragma unroll
  for (int j = 0; j < 16; j++) {
    float mx = red32_max(a[j]);
    e[j] = expf(a[j] - mx);
  }
  #pragma unroll
  for (int j = 0; j < 16; j++) s[j] = red32_sum(e[j]);
  #pragma unroll
  for (int j = 0; j < 16; j++) num[j] = red32_sum(e[j] * gfv[j]);
  if (n == 0) {
    float* orow = out + (size_t)pc * 131;
    #pragma unroll
    for (int j = 0; j < 16; j++) orow[3 + q * 16 + j] = num[j] / s[j];
    if (q == 0) {
      orow[0] = X[b * NPTS + cI]; orow[1] = Y[b * NPTS + cI]; orow[2] = Z[b * NPTS + cI];
    }
  }
}

// ---------------------------------------------------------------------------
extern "C" void kernel_launch(void* const* d_in, const int* in_sizes, int n_in,
                              void* d_out, int out_size, void* d_ws, size_t ws_size,
                              hipStream_t stream) {
  const float* points = (const float*)d_in[0];
  const float* W0 = (const float*)d_in[1];
  const float* B0 = (const float*)d_in[2];
  const float* G0 = (const float*)d_in[3];
  const float* E0 = (const float*)d_in[4];
  const float* W1 = (const float*)d_in[5];
  const float* B1 = (const float*)d_in[6];
  const float* G1 = (const float*)d_in[7];
  const float* E1 = (const float*)d_in[8];
  const float* W2 = (const float*)d_in[9];
  const float* B2 = (const float*)d_in[10];
  const float* G2 = (const float*)d_in[11];
  const float* E2 = (const float*)d_in[12];
  const float* Aatt = (const float*)d_in[13];
  float* out = (float*)d_out;

  // workspace (floats): mfeat 4.19M | P 4.19M | X/Y/Z 3*32k | cidx 8k | gidx 256k  (~35 MB)
  float* mfeat = (float*)d_ws;
  float* Pw = mfeat + (size_t)NBATCH * NPTS * 128;
  float* Xw = Pw + (size_t)NBATCH * NPTS * 128;
  float* Yw = Xw + NBATCH * NPTS;
  float* Zw = Yw + NBATCH * NPTS;
  int* cidxw = (int*)(Zw + NBATCH * NPTS);
  int* gidxw = cidxw + NBATCH * NPOINT;

  f1_kernel<<<8 + 64, 256, 0, stream>>>(points,
      W0, B0, G0, E0, W1, B1, G1, E1, W2, B2, G2, E2, Aatt,
      mfeat, Pw, cidxw, Xw, Yw, Zw);
  f2_kernel<<<NBATCH * NPOINT / 4, 256, 0, stream>>>(Xw, Yw, Zw, cidxw, gidxw);
  attn_kernel<<<NBATCH * NPOINT, 256, 0, stream>>>(Xw, Yw, Zw, mfeat, Pw, cidxw, gidxw, out);
}